// Round 5
// baseline (490.432 us; speedup 1.0000x reference)
//
#include <hip/hip_runtime.h>
#include <math.h>

#define N_NODES 50000
#define N_EDGES 800000
#define NUM_GRAPHS_ 128
#define SCAN_NB 98  // ceil(50000/512)

__device__ __forceinline__ float elu_f(float v) {
    return v > 0.f ? v : (__expf(v) - 1.f);
}

// ---------------------------------------------------------------------------
// ew[e] = edge_attr[e,:16] . w_fc1 + b_fc1 ;  deg[dst] += 1
// ---------------------------------------------------------------------------
__global__ void ew_deg_kernel(const float* __restrict__ edge_attr,
                              const float* __restrict__ w_fc1,
                              const float* __restrict__ b_fc1,
                              const int* __restrict__ edge_index,
                              float* __restrict__ ew,
                              int* __restrict__ deg) {
    int e = blockIdx.x * blockDim.x + threadIdx.x;
    if (e >= N_EDGES) return;
    const float4* ea = (const float4*)(edge_attr + (size_t)e * 16);
    const float4* wf = (const float4*)w_fc1;
    float acc = b_fc1[0];
#pragma unroll
    for (int i = 0; i < 4; i++) {
        float4 a = ea[i], w = wf[i];
        acc += a.x * w.x + a.y * w.y + a.z * w.z + a.w * w.w;
    }
    ew[e] = acc;
    atomicAdd(&deg[edge_index[N_EDGES + e]], 1);
}

// ---------------------------------------------------------------------------
// Hierarchical exclusive scan of deg[N] -> rowptr[N+1], cursor[N]
// ---------------------------------------------------------------------------
__global__ __launch_bounds__(256) void scan1_kernel(const int* __restrict__ deg,
                                                    int* __restrict__ rowptr,
                                                    int* __restrict__ blk_sums) {
    __shared__ int sh[256];
    const int t = threadIdx.x;
    const int base = blockIdx.x * 512;
    const int i0 = base + 2 * t, i1 = i0 + 1;
    const int d0 = (i0 < N_NODES) ? deg[i0] : 0;
    const int d1 = (i1 < N_NODES) ? deg[i1] : 0;
    const int pair = d0 + d1;
    int v = pair;
    sh[t] = v;
    __syncthreads();
#pragma unroll
    for (int off = 1; off < 256; off <<= 1) {
        int add = (t >= off) ? sh[t - off] : 0;
        __syncthreads();
        v += add;
        sh[t] = v;
        __syncthreads();
    }
    const int excl = v - pair;
    if (i0 < N_NODES) rowptr[i0] = excl;
    if (i1 < N_NODES) rowptr[i1] = excl + d0;
    if (t == 255) blk_sums[blockIdx.x] = v;
}

__global__ __launch_bounds__(128) void scan2_kernel(const int* __restrict__ blk_sums,
                                                    int* __restrict__ blk_offs,
                                                    int* __restrict__ rowptr) {
    __shared__ int sh[128];
    const int t = threadIdx.x;
    const int orig = (t < SCAN_NB) ? blk_sums[t] : 0;
    int v = orig;
    sh[t] = v;
    __syncthreads();
#pragma unroll
    for (int off = 1; off < 128; off <<= 1) {
        int add = (t >= off) ? sh[t - off] : 0;
        __syncthreads();
        v += add;
        sh[t] = v;
        __syncthreads();
    }
    if (t < SCAN_NB) blk_offs[t] = v - orig;
    if (t == 127) rowptr[N_NODES] = v;
}

__global__ void scan3_kernel(int* __restrict__ rowptr,
                             const int* __restrict__ blk_offs,
                             int* __restrict__ cursor) {
    int i = blockIdx.x * blockDim.x + threadIdx.x;
    if (i >= N_NODES) return;
    int r = rowptr[i] + blk_offs[i >> 9];
    rowptr[i] = r;
    cursor[i] = r;
}

// ---------------------------------------------------------------------------
// CSR placement with PACKED entries: csr[pos] = {src, bits(w)}
// ---------------------------------------------------------------------------
__global__ void place_kernel(const int* __restrict__ edge_index,
                             const float* __restrict__ ew,
                             int* __restrict__ cursor,
                             int2* __restrict__ csr) {
    int e = blockIdx.x * blockDim.x + threadIdx.x;
    if (e >= N_EDGES) return;
    int dst = edge_index[N_EDGES + e];
    int pos = atomicAdd(&cursor[dst], 1);
    int2 ent;
    ent.x = edge_index[e];
    ent.y = __float_as_int(ew[e]);
    csr[pos] = ent;
}

// ---------------------------------------------------------------------------
// Gather aggregation, one WAVE (64 lanes) per node.
// ---------------------------------------------------------------------------
template <int DIN, bool WRITE_C>
__global__ __launch_bounds__(256) void gather_kernel(
    const float* __restrict__ x, const int* __restrict__ rowptr,
    const int2* __restrict__ csr, float* __restrict__ s,
    float* __restrict__ c) {
    constexpr int CG = DIN / 4;   // 16 (DIN=64) or 32 (DIN=128)
    constexpr int EG = 64 / CG;   // 4 or 2
    const int gid = blockIdx.x * 256 + threadIdx.x;
    const int node = gid >> 6;
    if (node >= N_NODES) return;
    const int lane = threadIdx.x & 63;
    const int cg = lane & (CG - 1);
    const int eg = lane / CG;
    const int beg = rowptr[node];
    const int end = rowptr[node + 1];
    const float4* x4 = (const float4*)x;

    float4 a0 = make_float4(0.f, 0.f, 0.f, 0.f);
    float4 a1 = make_float4(0.f, 0.f, 0.f, 0.f);
    float wsum = 0.f;

    int p = beg + eg;
    for (; p + EG < end; p += 2 * EG) {
        int2 e0 = csr[p];
        int2 e1 = csr[p + EG];
        float w0 = __int_as_float(e0.y);
        float w1 = __int_as_float(e1.y);
        float4 v0 = x4[(size_t)e0.x * CG + cg];
        float4 v1 = x4[(size_t)e1.x * CG + cg];
        a0.x += w0 * v0.x; a0.y += w0 * v0.y; a0.z += w0 * v0.z; a0.w += w0 * v0.w;
        a1.x += w1 * v1.x; a1.y += w1 * v1.y; a1.z += w1 * v1.z; a1.w += w1 * v1.w;
        wsum += w0 + w1;
    }
    if (p < end) {
        int2 e0 = csr[p];
        float w0 = __int_as_float(e0.y);
        float4 v0 = x4[(size_t)e0.x * CG + cg];
        a0.x += w0 * v0.x; a0.y += w0 * v0.y; a0.z += w0 * v0.z; a0.w += w0 * v0.w;
        wsum += w0;
    }
    a0.x += a1.x; a0.y += a1.y; a0.z += a1.z; a0.w += a1.w;

#pragma unroll
    for (int off = 32; off >= CG; off >>= 1) {
        a0.x += __shfl_xor(a0.x, off);
        a0.y += __shfl_xor(a0.y, off);
        a0.z += __shfl_xor(a0.z, off);
        a0.w += __shfl_xor(a0.w, off);
        if (WRITE_C) wsum += __shfl_xor(wsum, off);
    }
    if (lane < CG) ((float4*)s)[(size_t)node * CG + cg] = a0;
    if (WRITE_C && lane == 0) c[node] = wsum;
}

// ---------------------------------------------------------------------------
// xout = elu( [x | s | c*x] @ [w3 ; w1 ; -w2] + b3 + c*b1 )
// BM=64, BN=32, BK=16, 256 threads, 4x2 regs/thread.
// grid = (ceil(N/64), DOUT/32) -> 1564..3128 blocks for occupancy.
// A staged with am=tid&63 (2 lanes/bank LDS writes = free; 4 waves tile the
// same cache lines -> full line utilization via L1).
// ---------------------------------------------------------------------------
template <int DIN, int DOUT>
__global__ __launch_bounds__(256) void leconv_gemm(
    const float* __restrict__ xin, const float* __restrict__ s,
    const float* __restrict__ c,
    const float* __restrict__ w1, const float* __restrict__ b1,
    const float* __restrict__ w2, const float* __restrict__ w3,
    const float* __restrict__ b3, float* __restrict__ xout) {
    constexpr int K = 3 * DIN;
    constexpr int BM = 64, BN = 32, BK = 16;
    __shared__ float As[BK][BM];
    __shared__ float Bs[BK][BN];
    const int tid = threadIdx.x;
    const int row0 = blockIdx.x * BM;
    const int col0 = blockIdx.y * BN;

    // A staging: lane -> row am (fast), k-group akg = wave index
    const int am = tid & 63;
    const int akg = tid >> 6;     // 0..3
    // B staging: threads 0..127, one float4 each
    const int bk = tid >> 3;      // 0..15 (for tid<128)
    const int bcg = tid & 7;      // 0..7
    // compute mapping: 16x16 threads, 4 rows x 2 cols each
    const int tm = tid >> 4;      // 0..15
    const int tn = tid & 15;      // 0..15

    const int arow = row0 + am;
    const bool arow_ok = arow < N_NODES;
    const float crow_a = arow_ok ? c[arow] : 0.f;

    float acc[4][2] = {};

    for (int k0 = 0; k0 < K; k0 += BK) {
        const int region = k0 / DIN;  // BK chunk never straddles regions
        // ---- load A frag (float4 along k)
        float4 av = make_float4(0.f, 0.f, 0.f, 0.f);
        if (arow_ok) {
            const int koff = k0 - region * DIN + akg * 4;
            const float* srcp = (region == 1) ? (s + (size_t)arow * DIN + koff)
                                              : (xin + (size_t)arow * DIN + koff);
            av = *(const float4*)srcp;
            if (region == 2) {
                av.x *= crow_a; av.y *= crow_a; av.z *= crow_a; av.w *= crow_a;
            }
        }
        // ---- load B frag (threads 0..127)
        float4 bv;
        if (tid < 128) {
            const int kboff = (k0 - region * DIN) + bk;
            const float* wsrc = (region == 0) ? w3 : (region == 1 ? w1 : w2);
            bv = *(const float4*)(wsrc + (size_t)kboff * DOUT + col0 + bcg * 4);
            if (region == 2) { bv.x = -bv.x; bv.y = -bv.y; bv.z = -bv.z; bv.w = -bv.w; }
        }

        __syncthreads();  // previous tile consumed
        As[akg * 4 + 0][am] = av.x;
        As[akg * 4 + 1][am] = av.y;
        As[akg * 4 + 2][am] = av.z;
        As[akg * 4 + 3][am] = av.w;
        if (tid < 128) *(float4*)&Bs[bk][bcg * 4] = bv;
        __syncthreads();

#pragma unroll
        for (int kk = 0; kk < BK; kk++) {
            float4 a4 = *(const float4*)&As[kk][tm * 4];
            float2 b2 = *(const float2*)&Bs[kk][tn * 2];
            float ar[4] = {a4.x, a4.y, a4.z, a4.w};
#pragma unroll
            for (int i = 0; i < 4; i++) {
                acc[i][0] += ar[i] * b2.x;
                acc[i][1] += ar[i] * b2.y;
            }
        }
    }

    // ---- epilogue: + b3 + c*b1, ELU, store (float2)
    const int col = col0 + tn * 2;
    const float b3x = b3[col], b3y = b3[col + 1];
    const float b1x = b1[col], b1y = b1[col + 1];
#pragma unroll
    for (int i = 0; i < 4; i++) {
        const int row = row0 + tm * 4 + i;
        if (row >= N_NODES) break;
        const float cr = c[row];
        float2 o;
        o.x = elu_f(acc[i][0] + b3x + cr * b1x);
        o.y = elu_f(acc[i][1] + b3y + cr * b1y);
        *(float2*)(xout + (size_t)row * DOUT + col) = o;
    }
}

// ---------------------------------------------------------------------------
// out[g, :] = max over nodes of graph g of h[:, :64]; batch is sorted.
// ---------------------------------------------------------------------------
__global__ void pool_kernel(const float* __restrict__ h,
                            const int* __restrict__ batch,
                            float* __restrict__ out) {
    const int g = blockIdx.x;
    const int tid = threadIdx.x;
    int lo = 0, hi = N_NODES;
    while (lo < hi) { int mid = (lo + hi) >> 1; if (batch[mid] < g) lo = mid + 1; else hi = mid; }
    const int beg = lo;
    lo = beg; hi = N_NODES;
    while (lo < hi) { int mid = (lo + hi) >> 1; if (batch[mid] < g + 1) lo = mid + 1; else hi = mid; }
    const int end = lo;

    __shared__ float red[256];
    const int col = tid & 63;
    const int rg = tid >> 6;
    float m = -3.0e38f;
    for (int r = beg + rg; r < end; r += 4) m = fmaxf(m, h[(size_t)r * 64 + col]);
    red[tid] = m;
    __syncthreads();
    if (tid < 64) {
        m = fmaxf(fmaxf(red[tid], red[tid + 64]), fmaxf(red[tid + 128], red[tid + 192]));
        out[g * 64 + tid] = m;
    }
}

extern "C" void kernel_launch(void* const* d_in, const int* in_sizes, int n_in,
                              void* d_out, int out_size, void* d_ws, size_t ws_size,
                              hipStream_t stream) {
    const float* x = (const float*)d_in[0];
    const int* ei = (const int*)d_in[1];
    const float* ea = (const float*)d_in[2];
    const int* batch = (const int*)d_in[3];
    const float* wfc = (const float*)d_in[4];
    const float* bfc = (const float*)d_in[5];
    const float* w1_0 = (const float*)d_in[6];
    const float* b1_0 = (const float*)d_in[7];
    const float* w2_0 = (const float*)d_in[8];
    const float* w3_0 = (const float*)d_in[9];
    const float* b3_0 = (const float*)d_in[10];
    const float* w1_1 = (const float*)d_in[11];
    const float* b1_1 = (const float*)d_in[12];
    const float* w2_1 = (const float*)d_in[13];
    const float* w3_1 = (const float*)d_in[14];
    const float* b3_1 = (const float*)d_in[15];
    const float* w1_2 = (const float*)d_in[16];
    const float* b1_2 = (const float*)d_in[17];
    const float* w2_2 = (const float*)d_in[18];
    const float* w3_2 = (const float*)d_in[19];
    const float* b3_2 = (const float*)d_in[20];
    float* out = (float*)d_out;

    char* ws = (char*)d_ws;
    float* ew      = (float*)(ws);                 // E floats   (3.2 MB)
    float* c       = (float*)(ws + 3200000);       // N floats (written by gather0)
    int*   deg     = (int*)  (ws + 3400000);       // N ints
    int*   cursor  = (int*)  (ws + 3600000);       // N ints
    int*   rowptr  = (int*)  (ws + 3800000);       // N+1 ints
    int2*  csr     = (int2*) (ws + 4000128);       // E int2     (6.4 MB)
    float* s       = (float*)(ws + 10400128);      // N*128 floats (25.6 MB)
    float* hA      = (float*)(ws + 36000128);      // N*64 floats  (12.8 MB)
    float* hB      = (float*)(ws + 48800128);      // N*128 floats (25.6 MB)
    int* blk_sums = (int*)s;       // scan scratch, free until gathers run
    int* blk_offs = (int*)s + 128;

    hipMemsetAsync(deg, 0, N_NODES * sizeof(int), stream);

    ew_deg_kernel<<<(N_EDGES + 255) / 256, 256, 0, stream>>>(ea, wfc, bfc, ei, ew, deg);
    scan1_kernel<<<SCAN_NB, 256, 0, stream>>>(deg, rowptr, blk_sums);
    scan2_kernel<<<1, 128, 0, stream>>>(blk_sums, blk_offs, rowptr);
    scan3_kernel<<<(N_NODES + 255) / 256, 256, 0, stream>>>(rowptr, blk_offs, cursor);
    place_kernel<<<(N_EDGES + 255) / 256, 256, 0, stream>>>(ei, ew, cursor, csr);

    const int RB = (N_NODES + 63) / 64;           // 782 row-blocks
    dim3 g64(RB, 2);   // DOUT=64  -> 2 col-blocks of 32
    dim3 g128(RB, 4);  // DOUT=128 -> 4 col-blocks of 32
    const int GBLK = (N_NODES * 64 + 255) / 256;  // one wave per node

    // layer 0: 64 -> 64, in x, out hA (also emits c)
    gather_kernel<64, true><<<GBLK, 256, 0, stream>>>(x, rowptr, csr, s, c);
    leconv_gemm<64, 64><<<g64, 256, 0, stream>>>(x, s, c, w1_0, b1_0, w2_0, w3_0, b3_0, hA);

    // layer 1: 64 -> 128, in hA, out hB
    gather_kernel<64, false><<<GBLK, 256, 0, stream>>>(hA, rowptr, csr, s, c);
    leconv_gemm<64, 128><<<g128, 256, 0, stream>>>(hA, s, c, w1_1, b1_1, w2_1, w3_1, b3_1, hB);

    // layer 2: 128 -> 64, in hB, out hA
    gather_kernel<128, false><<<GBLK, 256, 0, stream>>>(hB, rowptr, csr, s, c);
    leconv_gemm<128, 64><<<g64, 256, 0, stream>>>(hB, s, c, w1_2, b1_2, w2_2, w3_2, b3_2, hA);

    // global max pool
    pool_kernel<<<NUM_GRAPHS_, 256, 0, stream>>>(hA, batch, out);
}

// Round 6
// 477.852 us; speedup vs baseline: 1.0263x; 1.0263x over previous
//
#include <hip/hip_runtime.h>
#include <math.h>

#define N_NODES 50000
#define N_EDGES 800000
#define NUM_GRAPHS_ 128
#define SCAN_NB 98  // ceil(50000/512)

__device__ __forceinline__ float elu_f(float v) {
    return v > 0.f ? v : (__expf(v) - 1.f);
}

// ---------------------------------------------------------------------------
// ew[e] = edge_attr[e,:16] . w_fc1 + b_fc1 ;  deg[dst] += 1
// ---------------------------------------------------------------------------
__global__ void ew_deg_kernel(const float* __restrict__ edge_attr,
                              const float* __restrict__ w_fc1,
                              const float* __restrict__ b_fc1,
                              const int* __restrict__ edge_index,
                              float* __restrict__ ew,
                              int* __restrict__ deg) {
    int e = blockIdx.x * blockDim.x + threadIdx.x;
    if (e >= N_EDGES) return;
    const float4* ea = (const float4*)(edge_attr + (size_t)e * 16);
    const float4* wf = (const float4*)w_fc1;
    float acc = b_fc1[0];
#pragma unroll
    for (int i = 0; i < 4; i++) {
        float4 a = ea[i], w = wf[i];
        acc += a.x * w.x + a.y * w.y + a.z * w.z + a.w * w.w;
    }
    ew[e] = acc;
    atomicAdd(&deg[edge_index[N_EDGES + e]], 1);
}

// ---------------------------------------------------------------------------
// Hierarchical exclusive scan of deg[N] -> rowptr[N+1], cursor[N]
// ---------------------------------------------------------------------------
__global__ __launch_bounds__(256) void scan1_kernel(const int* __restrict__ deg,
                                                    int* __restrict__ rowptr,
                                                    int* __restrict__ blk_sums) {
    __shared__ int sh[256];
    const int t = threadIdx.x;
    const int base = blockIdx.x * 512;
    const int i0 = base + 2 * t, i1 = i0 + 1;
    const int d0 = (i0 < N_NODES) ? deg[i0] : 0;
    const int d1 = (i1 < N_NODES) ? deg[i1] : 0;
    const int pair = d0 + d1;
    int v = pair;
    sh[t] = v;
    __syncthreads();
#pragma unroll
    for (int off = 1; off < 256; off <<= 1) {
        int add = (t >= off) ? sh[t - off] : 0;
        __syncthreads();
        v += add;
        sh[t] = v;
        __syncthreads();
    }
    const int excl = v - pair;
    if (i0 < N_NODES) rowptr[i0] = excl;
    if (i1 < N_NODES) rowptr[i1] = excl + d0;
    if (t == 255) blk_sums[blockIdx.x] = v;
}

__global__ __launch_bounds__(128) void scan2_kernel(const int* __restrict__ blk_sums,
                                                    int* __restrict__ blk_offs,
                                                    int* __restrict__ rowptr) {
    __shared__ int sh[128];
    const int t = threadIdx.x;
    const int orig = (t < SCAN_NB) ? blk_sums[t] : 0;
    int v = orig;
    sh[t] = v;
    __syncthreads();
#pragma unroll
    for (int off = 1; off < 128; off <<= 1) {
        int add = (t >= off) ? sh[t - off] : 0;
        __syncthreads();
        v += add;
        sh[t] = v;
        __syncthreads();
    }
    if (t < SCAN_NB) blk_offs[t] = v - orig;
    if (t == 127) rowptr[N_NODES] = v;
}

__global__ void scan3_kernel(int* __restrict__ rowptr,
                             const int* __restrict__ blk_offs,
                             int* __restrict__ cursor) {
    int i = blockIdx.x * blockDim.x + threadIdx.x;
    if (i >= N_NODES) return;
    int r = rowptr[i] + blk_offs[i >> 9];
    rowptr[i] = r;
    cursor[i] = r;
}

// ---------------------------------------------------------------------------
// CSR placement with PACKED entries: csr[pos] = {src, bits(w)}
// ---------------------------------------------------------------------------
__global__ void place_kernel(const int* __restrict__ edge_index,
                             const float* __restrict__ ew,
                             int* __restrict__ cursor,
                             int2* __restrict__ csr) {
    int e = blockIdx.x * blockDim.x + threadIdx.x;
    if (e >= N_EDGES) return;
    int dst = edge_index[N_EDGES + e];
    int pos = atomicAdd(&cursor[dst], 1);
    int2 ent;
    ent.x = edge_index[e];
    ent.y = __float_as_int(ew[e]);
    csr[pos] = ent;
}

// ---------------------------------------------------------------------------
// Gather aggregation, one WAVE (64 lanes) per node.
// ---------------------------------------------------------------------------
template <int DIN, bool WRITE_C>
__global__ __launch_bounds__(256) void gather_kernel(
    const float* __restrict__ x, const int* __restrict__ rowptr,
    const int2* __restrict__ csr, float* __restrict__ s,
    float* __restrict__ c) {
    constexpr int CG = DIN / 4;   // 16 (DIN=64) or 32 (DIN=128)
    constexpr int EG = 64 / CG;   // 4 or 2
    const int gid = blockIdx.x * 256 + threadIdx.x;
    const int node = gid >> 6;
    if (node >= N_NODES) return;
    const int lane = threadIdx.x & 63;
    const int cg = lane & (CG - 1);
    const int eg = lane / CG;
    const int beg = rowptr[node];
    const int end = rowptr[node + 1];
    const float4* x4 = (const float4*)x;

    float4 a0 = make_float4(0.f, 0.f, 0.f, 0.f);
    float4 a1 = make_float4(0.f, 0.f, 0.f, 0.f);
    float wsum = 0.f;

    int p = beg + eg;
    for (; p + EG < end; p += 2 * EG) {
        int2 e0 = csr[p];
        int2 e1 = csr[p + EG];
        float w0 = __int_as_float(e0.y);
        float w1 = __int_as_float(e1.y);
        float4 v0 = x4[(size_t)e0.x * CG + cg];
        float4 v1 = x4[(size_t)e1.x * CG + cg];
        a0.x += w0 * v0.x; a0.y += w0 * v0.y; a0.z += w0 * v0.z; a0.w += w0 * v0.w;
        a1.x += w1 * v1.x; a1.y += w1 * v1.y; a1.z += w1 * v1.z; a1.w += w1 * v1.w;
        wsum += w0 + w1;
    }
    if (p < end) {
        int2 e0 = csr[p];
        float w0 = __int_as_float(e0.y);
        float4 v0 = x4[(size_t)e0.x * CG + cg];
        a0.x += w0 * v0.x; a0.y += w0 * v0.y; a0.z += w0 * v0.z; a0.w += w0 * v0.w;
        wsum += w0;
    }
    a0.x += a1.x; a0.y += a1.y; a0.z += a1.z; a0.w += a1.w;

#pragma unroll
    for (int off = 32; off >= CG; off >>= 1) {
        a0.x += __shfl_xor(a0.x, off);
        a0.y += __shfl_xor(a0.y, off);
        a0.z += __shfl_xor(a0.z, off);
        a0.w += __shfl_xor(a0.w, off);
        if (WRITE_C) wsum += __shfl_xor(wsum, off);
    }
    if (lane < CG) ((float4*)s)[(size_t)node * CG + cg] = a0;
    if (WRITE_C && lane == 0) c[node] = wsum;
}

// ---------------------------------------------------------------------------
// xout = elu( [x | s | c*x] @ [w3 ; w1 ; -w2] + b3 + c*b1 )
// BM=32, BN=64, BK=16, 256 threads, 2x4 regs/thread.
// grid = (ceil(N/32)=1563, DOUT/64) -> high occupancy, A fetched ~once.
// A staging: threads 0..127, 4 lanes/row (coalesced 64B lines), transposed
// store into As[BK][BM+4] -> stride 36 -> 2 lanes/bank (free).
// B staging: all 256 threads, coalesced, Bs stride 64 -> 2 lanes/bank (free).
// ---------------------------------------------------------------------------
template <int DIN, int DOUT>
__global__ __launch_bounds__(256) void leconv_gemm(
    const float* __restrict__ xin, const float* __restrict__ s,
    const float* __restrict__ c,
    const float* __restrict__ w1, const float* __restrict__ b1,
    const float* __restrict__ w2, const float* __restrict__ w3,
    const float* __restrict__ b3, float* __restrict__ xout) {
    constexpr int K = 3 * DIN;
    constexpr int BM = 32, BN = 64, BK = 16;
    __shared__ float As[BK][BM + 4];
    __shared__ float Bs[BK][BN];
    const int tid = threadIdx.x;
    const int row0 = blockIdx.x * BM;
    const int col0 = blockIdx.y * BN;

    // A staging (threads 0..127): row am, k-group akg (float4 along k)
    const int am = (tid & 127) >> 2;  // 0..31
    const int akg = tid & 3;          // 0..3
    const bool a_stager = (tid < 128);
    // B staging (all 256): k-row bk, col-group bcg (float4 along cols)
    const int bk = tid >> 4;          // 0..15
    const int bcg = tid & 15;         // 0..15
    // compute mapping: 16x16 threads, 2 rows x 4 cols each
    const int tm = tid >> 4;          // 0..15
    const int tn = tid & 15;          // 0..15

    const int arow = row0 + am;
    const bool arow_ok = a_stager && (arow < N_NODES);
    const float crow_a = arow_ok ? c[arow] : 0.f;

    float acc[2][4] = {};

    for (int k0 = 0; k0 < K; k0 += BK) {
        const int region = k0 / DIN;  // BK chunk never straddles regions
        // ---- load A frag (float4 along k), coalesced
        float4 av = make_float4(0.f, 0.f, 0.f, 0.f);
        if (arow_ok) {
            const int koff = k0 - region * DIN + akg * 4;
            const float* srcp = (region == 1) ? (s + (size_t)arow * DIN + koff)
                                              : (xin + (size_t)arow * DIN + koff);
            av = *(const float4*)srcp;
            if (region == 2) {
                av.x *= crow_a; av.y *= crow_a; av.z *= crow_a; av.w *= crow_a;
            }
        }
        // ---- load B frag, coalesced (256B per k-row)
        const int kboff = (k0 - region * DIN) + bk;
        const float* wsrc = (region == 0) ? w3 : (region == 1 ? w1 : w2);
        float4 bv = *(const float4*)(wsrc + (size_t)kboff * DOUT + col0 + bcg * 4);
        if (region == 2) { bv.x = -bv.x; bv.y = -bv.y; bv.z = -bv.z; bv.w = -bv.w; }

        __syncthreads();  // previous tile consumed
        if (a_stager) {
            As[akg * 4 + 0][am] = av.x;
            As[akg * 4 + 1][am] = av.y;
            As[akg * 4 + 2][am] = av.z;
            As[akg * 4 + 3][am] = av.w;
        }
        *(float4*)&Bs[bk][bcg * 4] = bv;
        __syncthreads();

#pragma unroll
        for (int kk = 0; kk < BK; kk++) {
            float2 a2 = *(const float2*)&As[kk][tm * 2];
            float4 b4 = *(const float4*)&Bs[kk][tn * 4];
            acc[0][0] += a2.x * b4.x; acc[0][1] += a2.x * b4.y;
            acc[0][2] += a2.x * b4.z; acc[0][3] += a2.x * b4.w;
            acc[1][0] += a2.y * b4.x; acc[1][1] += a2.y * b4.y;
            acc[1][2] += a2.y * b4.z; acc[1][3] += a2.y * b4.w;
        }
    }

    // ---- epilogue: + b3 + c*b1, ELU, store (float4)
    const int col = col0 + tn * 4;
    const float4 b3v = *(const float4*)(b3 + col);
    const float4 b1v = *(const float4*)(b1 + col);
#pragma unroll
    for (int i = 0; i < 2; i++) {
        const int row = row0 + tm * 2 + i;
        if (row >= N_NODES) break;
        const float cr = c[row];
        float4 o;
        o.x = elu_f(acc[i][0] + b3v.x + cr * b1v.x);
        o.y = elu_f(acc[i][1] + b3v.y + cr * b1v.y);
        o.z = elu_f(acc[i][2] + b3v.z + cr * b1v.z);
        o.w = elu_f(acc[i][3] + b3v.w + cr * b1v.w);
        *(float4*)(xout + (size_t)row * DOUT + col) = o;
    }
}

// ---------------------------------------------------------------------------
// out[g, :] = max over nodes of graph g of h[:, :64]; batch is sorted.
// ---------------------------------------------------------------------------
__global__ void pool_kernel(const float* __restrict__ h,
                            const int* __restrict__ batch,
                            float* __restrict__ out) {
    const int g = blockIdx.x;
    const int tid = threadIdx.x;
    int lo = 0, hi = N_NODES;
    while (lo < hi) { int mid = (lo + hi) >> 1; if (batch[mid] < g) lo = mid + 1; else hi = mid; }
    const int beg = lo;
    lo = beg; hi = N_NODES;
    while (lo < hi) { int mid = (lo + hi) >> 1; if (batch[mid] < g + 1) lo = mid + 1; else hi = mid; }
    const int end = lo;

    __shared__ float red[256];
    const int col = tid & 63;
    const int rg = tid >> 6;
    float m = -3.0e38f;
    for (int r = beg + rg; r < end; r += 4) m = fmaxf(m, h[(size_t)r * 64 + col]);
    red[tid] = m;
    __syncthreads();
    if (tid < 64) {
        m = fmaxf(fmaxf(red[tid], red[tid + 64]), fmaxf(red[tid + 128], red[tid + 192]));
        out[g * 64 + tid] = m;
    }
}

extern "C" void kernel_launch(void* const* d_in, const int* in_sizes, int n_in,
                              void* d_out, int out_size, void* d_ws, size_t ws_size,
                              hipStream_t stream) {
    const float* x = (const float*)d_in[0];
    const int* ei = (const int*)d_in[1];
    const float* ea = (const float*)d_in[2];
    const int* batch = (const int*)d_in[3];
    const float* wfc = (const float*)d_in[4];
    const float* bfc = (const float*)d_in[5];
    const float* w1_0 = (const float*)d_in[6];
    const float* b1_0 = (const float*)d_in[7];
    const float* w2_0 = (const float*)d_in[8];
    const float* w3_0 = (const float*)d_in[9];
    const float* b3_0 = (const float*)d_in[10];
    const float* w1_1 = (const float*)d_in[11];
    const float* b1_1 = (const float*)d_in[12];
    const float* w2_1 = (const float*)d_in[13];
    const float* w3_1 = (const float*)d_in[14];
    const float* b3_1 = (const float*)d_in[15];
    const float* w1_2 = (const float*)d_in[16];
    const float* b1_2 = (const float*)d_in[17];
    const float* w2_2 = (const float*)d_in[18];
    const float* w3_2 = (const float*)d_in[19];
    const float* b3_2 = (const float*)d_in[20];
    float* out = (float*)d_out;

    char* ws = (char*)d_ws;
    float* ew      = (float*)(ws);                 // E floats   (3.2 MB)
    float* c       = (float*)(ws + 3200000);       // N floats (written by gather0)
    int*   deg     = (int*)  (ws + 3400000);       // N ints
    int*   cursor  = (int*)  (ws + 3600000);       // N ints
    int*   rowptr  = (int*)  (ws + 3800000);       // N+1 ints
    int2*  csr     = (int2*) (ws + 4000128);       // E int2     (6.4 MB)
    float* s       = (float*)(ws + 10400128);      // N*128 floats (25.6 MB)
    float* hA      = (float*)(ws + 36000128);      // N*64 floats  (12.8 MB)
    float* hB      = (float*)(ws + 48800128);      // N*128 floats (25.6 MB)
    int* blk_sums = (int*)s;       // scan scratch, free until gathers run
    int* blk_offs = (int*)s + 128;

    hipMemsetAsync(deg, 0, N_NODES * sizeof(int), stream);

    ew_deg_kernel<<<(N_EDGES + 255) / 256, 256, 0, stream>>>(ea, wfc, bfc, ei, ew, deg);
    scan1_kernel<<<SCAN_NB, 256, 0, stream>>>(deg, rowptr, blk_sums);
    scan2_kernel<<<1, 128, 0, stream>>>(blk_sums, blk_offs, rowptr);
    scan3_kernel<<<(N_NODES + 255) / 256, 256, 0, stream>>>(rowptr, blk_offs, cursor);
    place_kernel<<<(N_EDGES + 255) / 256, 256, 0, stream>>>(ei, ew, cursor, csr);

    const int RB = (N_NODES + 31) / 32;           // 1563 row-blocks
    dim3 g64(RB, 1);   // DOUT=64  -> 1 col-block of 64
    dim3 g128(RB, 2);  // DOUT=128 -> 2 col-blocks of 64
    const int GBLK = (N_NODES * 64 + 255) / 256;  // one wave per node

    // layer 0: 64 -> 64, in x, out hA (also emits c)
    gather_kernel<64, true><<<GBLK, 256, 0, stream>>>(x, rowptr, csr, s, c);
    leconv_gemm<64, 64><<<g64, 256, 0, stream>>>(x, s, c, w1_0, b1_0, w2_0, w3_0, b3_0, hA);

    // layer 1: 64 -> 128, in hA, out hB
    gather_kernel<64, false><<<GBLK, 256, 0, stream>>>(hA, rowptr, csr, s, c);
    leconv_gemm<64, 128><<<g128, 256, 0, stream>>>(hA, s, c, w1_1, b1_1, w2_1, w3_1, b3_1, hB);

    // layer 2: 128 -> 64, in hB, out hA
    gather_kernel<128, false><<<GBLK, 256, 0, stream>>>(hB, rowptr, csr, s, c);
    leconv_gemm<128, 64><<<g64, 256, 0, stream>>>(hB, s, c, w1_2, b1_2, w2_2, w3_2, b3_2, hA);

    // global max pool
    pool_kernel<<<NUM_GRAPHS_, 256, 0, stream>>>(hA, batch, out);
}

// Round 7
// 387.949 us; speedup vs baseline: 1.2642x; 1.2317x over previous
//
#include <hip/hip_runtime.h>
#include <math.h>

#define N_NODES 50000
#define N_EDGES 800000
#define NUM_GRAPHS_ 128
#define SCAN_NB 98  // ceil(50000/512)

typedef unsigned short u16;
typedef unsigned int u32;
typedef __attribute__((ext_vector_type(8))) short bf16x8;   // 8 bf16 (4 VGPRs)
typedef __attribute__((ext_vector_type(4))) float f32x4;    // 4 fp32

__device__ __forceinline__ float elu_f(float v) {
    return v > 0.f ? v : (__expf(v) - 1.f);
}
__device__ __forceinline__ u16 f2bf(float f) {  // RNE
    u32 u = __float_as_uint(f);
    u += 0x7FFFu + ((u >> 16) & 1u);
    return (u16)(u >> 16);
}
__device__ __forceinline__ float bf2f(u16 h) {
    return __uint_as_float(((u32)h) << 16);
}
// unpack 2 bf16 packed in a u32 (little-endian: low half = element k)
__device__ __forceinline__ void bfpair(u32 v, float& lo, float& hi) {
    lo = __uint_as_float(v << 16);
    hi = __uint_as_float(v & 0xFFFF0000u);
}
__device__ __forceinline__ u32 packbf(float lo, float hi) {
    return (u32)f2bf(lo) | ((u32)f2bf(hi) << 16);
}

// ---------------------------------------------------------------------------
// xb = bf16(x), N*64 elements, 4 per thread
// ---------------------------------------------------------------------------
__global__ void conv_x_kernel(const float* __restrict__ x, u16* __restrict__ xb) {
    int g = blockIdx.x * blockDim.x + threadIdx.x;  // 800000 groups of 4
    float4 v = ((const float4*)x)[g];
    uint2 o;
    o.x = packbf(v.x, v.y);
    o.y = packbf(v.z, v.w);
    ((uint2*)xb)[g] = o;
}

// ---------------------------------------------------------------------------
// ew[e] = edge_attr[e,:16] . w_fc1 + b_fc1 ;  deg[dst] += 1
// ---------------------------------------------------------------------------
__global__ void ew_deg_kernel(const float* __restrict__ edge_attr,
                              const float* __restrict__ w_fc1,
                              const float* __restrict__ b_fc1,
                              const int* __restrict__ edge_index,
                              float* __restrict__ ew,
                              int* __restrict__ deg) {
    int e = blockIdx.x * blockDim.x + threadIdx.x;
    if (e >= N_EDGES) return;
    const float4* ea = (const float4*)(edge_attr + (size_t)e * 16);
    const float4* wf = (const float4*)w_fc1;
    float acc = b_fc1[0];
#pragma unroll
    for (int i = 0; i < 4; i++) {
        float4 a = ea[i], w = wf[i];
        acc += a.x * w.x + a.y * w.y + a.z * w.z + a.w * w.w;
    }
    ew[e] = acc;
    atomicAdd(&deg[edge_index[N_EDGES + e]], 1);
}

// ---------------------------------------------------------------------------
// Pack weights [w3 ; w1 ; -w2] (fp32 row-major K x DOUT) into MFMA B-frag
// layout, bf16: frag (chunk, ntile) holds lanes' 8 elems contiguously.
// B-frag lane layout: n = ntile*16 + (lane&15), k = chunk*32 + (lane>>4)*8 + j
// One thread per (layer-lane): 1536 (L0) + 3072 (L1) + 3072 (L2) = 7680.
// ---------------------------------------------------------------------------
__global__ void pack_w_kernel(const float* __restrict__ w3_0, const float* __restrict__ w1_0, const float* __restrict__ w2_0,
                              const float* __restrict__ w3_1, const float* __restrict__ w1_1, const float* __restrict__ w2_1,
                              const float* __restrict__ w3_2, const float* __restrict__ w1_2, const float* __restrict__ w2_2,
                              u16* __restrict__ bp0, u16* __restrict__ bp1, u16* __restrict__ bp2) {
    int t = blockIdx.x * blockDim.x + threadIdx.x;
    if (t >= 7680) return;
    int DIN, DOUT, lid;
    const float *w3, *w1, *w2;
    u16* bp;
    if (t < 1536)      { DIN = 64;  DOUT = 64;  lid = t;        w3 = w3_0; w1 = w1_0; w2 = w2_0; bp = bp0; }
    else if (t < 4608) { DIN = 64;  DOUT = 128; lid = t - 1536; w3 = w3_1; w1 = w1_1; w2 = w2_1; bp = bp1; }
    else               { DIN = 128; DOUT = 64;  lid = t - 4608; w3 = w3_2; w1 = w1_2; w2 = w2_2; bp = bp2; }
    const int NT = DOUT / 16;
    const int lane = lid & 63;
    const int fragid = lid >> 6;
    const int chunk = fragid / NT;
    const int ntile = fragid % NT;
    const int n = ntile * 16 + (lane & 15);
    const int kbase = chunk * 32 + (lane >> 4) * 8;
    u16 buf[8];
#pragma unroll
    for (int j = 0; j < 8; j++) {
        int k = kbase + j;
        int region = k / DIN;
        int kk = k - region * DIN;
        float v = (region == 0) ? w3[kk * DOUT + n]
                : (region == 1) ? w1[kk * DOUT + n]
                                : -w2[kk * DOUT + n];
        buf[j] = f2bf(v);
    }
    *(bf16x8*)(bp + ((size_t)lid << 3)) = *(bf16x8*)buf;
}

// ---------------------------------------------------------------------------
// Hierarchical exclusive scan of deg[N] -> rowptr[N+1], cursor[N]
// ---------------------------------------------------------------------------
__global__ __launch_bounds__(256) void scan1_kernel(const int* __restrict__ deg,
                                                    int* __restrict__ rowptr,
                                                    int* __restrict__ blk_sums) {
    __shared__ int sh[256];
    const int t = threadIdx.x;
    const int base = blockIdx.x * 512;
    const int i0 = base + 2 * t, i1 = i0 + 1;
    const int d0 = (i0 < N_NODES) ? deg[i0] : 0;
    const int d1 = (i1 < N_NODES) ? deg[i1] : 0;
    const int pair = d0 + d1;
    int v = pair;
    sh[t] = v;
    __syncthreads();
#pragma unroll
    for (int off = 1; off < 256; off <<= 1) {
        int add = (t >= off) ? sh[t - off] : 0;
        __syncthreads();
        v += add;
        sh[t] = v;
        __syncthreads();
    }
    const int excl = v - pair;
    if (i0 < N_NODES) rowptr[i0] = excl;
    if (i1 < N_NODES) rowptr[i1] = excl + d0;
    if (t == 255) blk_sums[blockIdx.x] = v;
}

__global__ __launch_bounds__(128) void scan2_kernel(const int* __restrict__ blk_sums,
                                                    int* __restrict__ blk_offs,
                                                    int* __restrict__ rowptr) {
    __shared__ int sh[128];
    const int t = threadIdx.x;
    const int orig = (t < SCAN_NB) ? blk_sums[t] : 0;
    int v = orig;
    sh[t] = v;
    __syncthreads();
#pragma unroll
    for (int off = 1; off < 128; off <<= 1) {
        int add = (t >= off) ? sh[t - off] : 0;
        __syncthreads();
        v += add;
        sh[t] = v;
        __syncthreads();
    }
    if (t < SCAN_NB) blk_offs[t] = v - orig;
    if (t == 127) rowptr[N_NODES] = v;
}

__global__ void scan3_kernel(int* __restrict__ rowptr,
                             const int* __restrict__ blk_offs,
                             int* __restrict__ cursor) {
    int i = blockIdx.x * blockDim.x + threadIdx.x;
    if (i >= N_NODES) return;
    int r = rowptr[i] + blk_offs[i >> 9];
    rowptr[i] = r;
    cursor[i] = r;
}

// ---------------------------------------------------------------------------
// CSR placement: csr[pos] = {src, bits(w)}
// ---------------------------------------------------------------------------
__global__ void place_kernel(const int* __restrict__ edge_index,
                             const float* __restrict__ ew,
                             int* __restrict__ cursor,
                             int2* __restrict__ csr) {
    int e = blockIdx.x * blockDim.x + threadIdx.x;
    if (e >= N_EDGES) return;
    int dst = edge_index[N_EDGES + e];
    int pos = atomicAdd(&cursor[dst], 1);
    int2 ent;
    ent.x = edge_index[e];
    ent.y = __float_as_int(ew[e]);
    csr[pos] = ent;
}

// ---------------------------------------------------------------------------
// Gather aggregation (bf16 in/out, fp32 accumulate), one WAVE per node.
// Also writes ch[node] = c[node] * xin[node] (bf16) — the gemm's region 2.
// Layer 0 (WRITE_C) computes c[node] = sum of row weights and stores it.
// ---------------------------------------------------------------------------
template <int DIN, bool WRITE_C>
__global__ __launch_bounds__(256) void gather_kernel(
    const u16* __restrict__ xb, const int* __restrict__ rowptr,
    const int2* __restrict__ csr, u16* __restrict__ sb,
    u16* __restrict__ chb, float* __restrict__ c) {
    constexpr int CG = DIN / 4;   // uint2 (4 bf16) groups per row: 16 or 32
    constexpr int EG = 64 / CG;   // edge groups: 4 or 2
    const int gid = blockIdx.x * 256 + threadIdx.x;
    const int node = gid >> 6;
    if (node >= N_NODES) return;
    const int lane = threadIdx.x & 63;
    const int cg = lane & (CG - 1);
    const int eg = lane / CG;
    const int beg = rowptr[node];
    const int end = rowptr[node + 1];
    const uint2* x2 = (const uint2*)xb;

    float a0 = 0.f, a1 = 0.f, a2 = 0.f, a3 = 0.f;
    float b0 = 0.f, b1 = 0.f, b2 = 0.f, b3 = 0.f;
    float wsum = 0.f;

    int p = beg + eg;
    for (; p + EG < end; p += 2 * EG) {
        int2 e0 = csr[p];
        int2 e1 = csr[p + EG];
        float w0 = __int_as_float(e0.y);
        float w1 = __int_as_float(e1.y);
        uint2 v0 = x2[(size_t)e0.x * CG + cg];
        uint2 v1 = x2[(size_t)e1.x * CG + cg];
        float f0, f1, f2, f3, g0, g1, g2, g3;
        bfpair(v0.x, f0, f1); bfpair(v0.y, f2, f3);
        bfpair(v1.x, g0, g1); bfpair(v1.y, g2, g3);
        a0 += w0 * f0; a1 += w0 * f1; a2 += w0 * f2; a3 += w0 * f3;
        b0 += w1 * g0; b1 += w1 * g1; b2 += w1 * g2; b3 += w1 * g3;
        wsum += w0 + w1;
    }
    if (p < end) {
        int2 e0 = csr[p];
        float w0 = __int_as_float(e0.y);
        uint2 v0 = x2[(size_t)e0.x * CG + cg];
        float f0, f1, f2, f3;
        bfpair(v0.x, f0, f1); bfpair(v0.y, f2, f3);
        a0 += w0 * f0; a1 += w0 * f1; a2 += w0 * f2; a3 += w0 * f3;
        wsum += w0;
    }
    a0 += b0; a1 += b1; a2 += b2; a3 += b3;

    // reduce across edge-groups (xor masks >= CG keep cg fixed)
#pragma unroll
    for (int off = 32; off >= CG; off >>= 1) {
        a0 += __shfl_xor(a0, off);
        a1 += __shfl_xor(a1, off);
        a2 += __shfl_xor(a2, off);
        a3 += __shfl_xor(a3, off);
        wsum += __shfl_xor(wsum, off);
    }

    if (lane < CG) {
        uint2 so;
        so.x = packbf(a0, a1);
        so.y = packbf(a2, a3);
        ((uint2*)sb)[(size_t)node * CG + cg] = so;
        // ch = c[node] * own input row
        const float cn = WRITE_C ? wsum : c[node];
        uint2 hv = x2[(size_t)node * CG + cg];
        float h0, h1, h2, h3;
        bfpair(hv.x, h0, h1); bfpair(hv.y, h2, h3);
        uint2 co;
        co.x = packbf(cn * h0, cn * h1);
        co.y = packbf(cn * h2, cn * h3);
        ((uint2*)chb)[(size_t)node * CG + cg] = co;
    }
    if (WRITE_C && lane == 0) c[node] = wsum;
}

// ---------------------------------------------------------------------------
// MFMA GEMM: out = elu( [h | s | ch] @ Bp + b3 + c*b1 ),  bf16 in, fp32 acc.
// Bp pre-packed as [w3 ; w1 ; -w2] in B-frag layout.
// Block = 256 thr = 4 waves; block tile 64 rows x 64 cols.
// Wave w: rows (bx*64 + (w&1)*32), cols (by*64 + (w>>1)*32); per wave
// 2 m-tiles x 2 n-tiles of 16x16x32 MFMA, K = 3*DIN.
// A-frag: A[m=lane&15][k=quad*8+j]; D: row=(quad)*4+reg, col=lane&15.
// A panel/block = 24-48 KB -> L1-shared across the 4 waves.
// ---------------------------------------------------------------------------
template <int DIN, int DOUT>
__global__ __launch_bounds__(256) void gemm_mfma(
    const u16* __restrict__ hb, const u16* __restrict__ sb,
    const u16* __restrict__ chb, const u16* __restrict__ Bp,
    const float* __restrict__ cvec, const float* __restrict__ bias1,
    const float* __restrict__ bias3, u16* __restrict__ outp) {
    constexpr int CH = DIN / 32;       // chunks per region
    constexpr int CHUNKS = 3 * CH;     // total K chunks
    constexpr int NT = DOUT / 16;      // n-tiles across DOUT
    const int tid = threadIdx.x;
    const int wv = tid >> 6;
    const int lane = tid & 63;
    const int l15 = lane & 15;
    const int q = lane >> 4;
    const int mhalf = wv & 1;
    const int nhalf = wv >> 1;
    const int row_base = blockIdx.x * 64 + mhalf * 32;
    const int nt0 = blockIdx.y * 4 + nhalf * 2;

    const int r0 = min(row_base + l15, N_NODES - 1);
    const int r1 = min(row_base + 16 + l15, N_NODES - 1);
    const int qo = q * 8;

    f32x4 acc00 = {0.f, 0.f, 0.f, 0.f};
    f32x4 acc01 = {0.f, 0.f, 0.f, 0.f};
    f32x4 acc10 = {0.f, 0.f, 0.f, 0.f};
    f32x4 acc11 = {0.f, 0.f, 0.f, 0.f};

#pragma unroll
    for (int chunk = 0; chunk < CHUNKS; chunk++) {
        const int region = chunk / CH;
        const int koff = (chunk - region * CH) * 32 + qo;
        const u16* A = (region == 0) ? hb : (region == 1) ? sb : chb;
        bf16x8 a0 = *(const bf16x8*)(A + (size_t)r0 * DIN + koff);
        bf16x8 a1 = *(const bf16x8*)(A + (size_t)r1 * DIN + koff);
        const u16* bp = Bp + (((size_t)(chunk * NT + nt0) * 64 + lane) << 3);
        bf16x8 bf0 = *(const bf16x8*)bp;
        bf16x8 bf1 = *(const bf16x8*)(bp + 64 * 8);
        acc00 = __builtin_amdgcn_mfma_f32_16x16x32_bf16(a0, bf0, acc00, 0, 0, 0);
        acc01 = __builtin_amdgcn_mfma_f32_16x16x32_bf16(a0, bf1, acc01, 0, 0, 0);
        acc10 = __builtin_amdgcn_mfma_f32_16x16x32_bf16(a1, bf0, acc10, 0, 0, 0);
        acc11 = __builtin_amdgcn_mfma_f32_16x16x32_bf16(a1, bf1, acc11, 0, 0, 0);
    }

    // epilogue
#pragma unroll
    for (int ni = 0; ni < 2; ni++) {
        const int col = (nt0 + ni) * 16 + l15;
        const float B3 = bias3[col];
        const float B1 = bias1[col];
        const f32x4 am0 = ni ? acc01 : acc00;
        const f32x4 am1 = ni ? acc11 : acc10;
#pragma unroll
        for (int mi = 0; mi < 2; mi++) {
            const f32x4 av = mi ? am1 : am0;
#pragma unroll
            for (int reg = 0; reg < 4; reg++) {
                const int row = row_base + mi * 16 + q * 4 + reg;
                if (row < N_NODES) {
                    const float cv = cvec[row];
                    const float val = av[reg] + B3 + cv * B1;
                    outp[(size_t)row * DOUT + col] = f2bf(elu_f(val));
                }
            }
        }
    }
}

// ---------------------------------------------------------------------------
// out[g, :] = max over nodes of graph g of h[:, :64] (bf16 in, fp32 out)
// ---------------------------------------------------------------------------
__global__ void pool_kernel(const u16* __restrict__ h,
                            const int* __restrict__ batch,
                            float* __restrict__ out) {
    const int g = blockIdx.x;
    const int tid = threadIdx.x;
    int lo = 0, hi = N_NODES;
    while (lo < hi) { int mid = (lo + hi) >> 1; if (batch[mid] < g) lo = mid + 1; else hi = mid; }
    const int beg = lo;
    lo = beg; hi = N_NODES;
    while (lo < hi) { int mid = (lo + hi) >> 1; if (batch[mid] < g + 1) lo = mid + 1; else hi = mid; }
    const int end = lo;

    __shared__ float red[256];
    const int col = tid & 63;
    const int rg = tid >> 6;
    float m = -3.0e38f;
    for (int r = beg + rg; r < end; r += 4) m = fmaxf(m, bf2f(h[(size_t)r * 64 + col]));
    red[tid] = m;
    __syncthreads();
    if (tid < 64) {
        m = fmaxf(fmaxf(red[tid], red[tid + 64]), fmaxf(red[tid + 128], red[tid + 192]));
        out[g * 64 + tid] = m;
    }
}

extern "C" void kernel_launch(void* const* d_in, const int* in_sizes, int n_in,
                              void* d_out, int out_size, void* d_ws, size_t ws_size,
                              hipStream_t stream) {
    const float* x = (const float*)d_in[0];
    const int* ei = (const int*)d_in[1];
    const float* ea = (const float*)d_in[2];
    const int* batch = (const int*)d_in[3];
    const float* wfc = (const float*)d_in[4];
    const float* bfc = (const float*)d_in[5];
    const float* w1_0 = (const float*)d_in[6];
    const float* b1_0 = (const float*)d_in[7];
    const float* w2_0 = (const float*)d_in[8];
    const float* w3_0 = (const float*)d_in[9];
    const float* b3_0 = (const float*)d_in[10];
    const float* w1_1 = (const float*)d_in[11];
    const float* b1_1 = (const float*)d_in[12];
    const float* w2_1 = (const float*)d_in[13];
    const float* w3_1 = (const float*)d_in[14];
    const float* b3_1 = (const float*)d_in[15];
    const float* w1_2 = (const float*)d_in[16];
    const float* b1_2 = (const float*)d_in[17];
    const float* w2_2 = (const float*)d_in[18];
    const float* w3_2 = (const float*)d_in[19];
    const float* b3_2 = (const float*)d_in[20];
    float* out = (float*)d_out;

    char* ws = (char*)d_ws;
    float* ew      = (float*)(ws);                 // E f32      3.2 MB [dead after place]
    float* c       = (float*)(ws + 3200000);       // N f32
    int*   deg     = (int*)  (ws + 3400000);       // N int
    int*   cursor  = (int*)  (ws + 3600000);       // N int
    int*   rowptr  = (int*)  (ws + 3800000);       // N+1 int
    int2*  csr     = (int2*) (ws + 4000128);       // E int2     6.4 MB
    u16*   xb      = (u16*)  (ws + 10400128);      // N*64 bf16  6.4 MB
    u16*   sb      = (u16*)  (ws + 16800128);      // N*128 bf16 12.8 MB
    u16*   chb     = (u16*)  (ws + 29600128);      // N*128 bf16 12.8 MB (reused per layer)
    u16*   h1      = (u16*)  (ws + 42400128);      // N*64 bf16  6.4 MB
    u16*   h2      = (u16*)  (ws + 48800128);      // N*128 bf16 12.8 MB
    u16*   h3      = (u16*)  (ws + 61600128);      // N*64 bf16  6.4 MB
    u16*   bp0     = (u16*)  (ws + 68000128);      // 24 KB packed weights L0
    u16*   bp1     = (u16*)  (ws + 68024704);      // 48 KB L1
    u16*   bp2     = (u16*)  (ws + 68073856);      // 48 KB L2
    int* blk_sums  = (int*)  (ws + 68123008);
    int* blk_offs  = (int*)  (ws + 68123520);

    hipMemsetAsync(deg, 0, N_NODES * sizeof(int), stream);

    conv_x_kernel<<<3125, 256, 0, stream>>>(x, xb);
    ew_deg_kernel<<<(N_EDGES + 255) / 256, 256, 0, stream>>>(ea, wfc, bfc, ei, ew, deg);
    pack_w_kernel<<<30, 256, 0, stream>>>(w3_0, w1_0, w2_0, w3_1, w1_1, w2_1,
                                          w3_2, w1_2, w2_2, bp0, bp1, bp2);
    scan1_kernel<<<SCAN_NB, 256, 0, stream>>>(deg, rowptr, blk_sums);
    scan2_kernel<<<1, 128, 0, stream>>>(blk_sums, blk_offs, rowptr);
    scan3_kernel<<<(N_NODES + 255) / 256, 256, 0, stream>>>(rowptr, blk_offs, cursor);
    place_kernel<<<(N_EDGES + 255) / 256, 256, 0, stream>>>(ei, ew, cursor, csr);

    const int RB = (N_NODES + 63) / 64;           // 782 row-blocks
    const int GBLK = (N_NODES * 64 + 255) / 256;  // one wave per node

    // layer 0: 64 -> 64
    gather_kernel<64, true><<<GBLK, 256, 0, stream>>>(xb, rowptr, csr, sb, chb, c);
    gemm_mfma<64, 64><<<dim3(RB, 1), 256, 0, stream>>>(xb, sb, chb, bp0, c, b1_0, b3_0, h1);

    // layer 1: 64 -> 128
    gather_kernel<64, false><<<GBLK, 256, 0, stream>>>(h1, rowptr, csr, sb, chb, c);
    gemm_mfma<64, 128><<<dim3(RB, 2), 256, 0, stream>>>(h1, sb, chb, bp1, c, b1_1, b3_1, h2);

    // layer 2: 128 -> 64
    gather_kernel<128, false><<<GBLK, 256, 0, stream>>>(h2, rowptr, csr, sb, chb, c);
    gemm_mfma<128, 64><<<dim3(RB, 1), 256, 0, stream>>>(h2, sb, chb, bp2, c, b1_2, b3_2, h3);

    // global max pool
    pool_kernel<<<NUM_GRAPHS_, 256, 0, stream>>>(h3, batch, out);
}

// Round 8
// 383.385 us; speedup vs baseline: 1.2792x; 1.0119x over previous
//
#include <hip/hip_runtime.h>
#include <math.h>

#define N_NODES 50000
#define N_EDGES 800000
#define NUM_GRAPHS_ 128
#define SCAN_NB 98   // ceil(50000/512)
#define NPASS 8
#define NODES_PER_PASS 6250  // 50000/8

typedef unsigned short u16;
typedef unsigned int u32;
typedef __attribute__((ext_vector_type(8))) short bf16x8;   // 8 bf16 (4 VGPRs)
typedef __attribute__((ext_vector_type(4))) float f32x4;    // 4 fp32

__device__ __forceinline__ float elu_f(float v) {
    return v > 0.f ? v : (__expf(v) - 1.f);
}
__device__ __forceinline__ u16 f2bf(float f) {  // RNE
    u32 u = __float_as_uint(f);
    u += 0x7FFFu + ((u >> 16) & 1u);
    return (u16)(u >> 16);
}
__device__ __forceinline__ float bf2f(u16 h) {
    return __uint_as_float(((u32)h) << 16);
}
__device__ __forceinline__ void bfpair(u32 v, float& lo, float& hi) {
    lo = __uint_as_float(v << 16);
    hi = __uint_as_float(v & 0xFFFF0000u);
}
__device__ __forceinline__ u32 packbf(float lo, float hi) {
    return (u32)f2bf(lo) | ((u32)f2bf(hi) << 16);
}

// ---------------------------------------------------------------------------
// xb = bf16(x), N*64 elements, 4 per thread
// ---------------------------------------------------------------------------
__global__ void conv_x_kernel(const float* __restrict__ x, u16* __restrict__ xb) {
    int g = blockIdx.x * blockDim.x + threadIdx.x;
    float4 v = ((const float4*)x)[g];
    uint2 o;
    o.x = packbf(v.x, v.y);
    o.y = packbf(v.z, v.w);
    ((uint2*)xb)[g] = o;
}

// ---------------------------------------------------------------------------
// ew[e] = edge_attr[e,:16] . w_fc1 + b_fc1 ;  deg[dst] += 1 ; dst16[e] = dst
// ---------------------------------------------------------------------------
__global__ void ew_deg_kernel(const float* __restrict__ edge_attr,
                              const float* __restrict__ w_fc1,
                              const float* __restrict__ b_fc1,
                              const int* __restrict__ edge_index,
                              float* __restrict__ ew,
                              u16* __restrict__ dst16,
                              int* __restrict__ deg) {
    int e = blockIdx.x * blockDim.x + threadIdx.x;
    if (e >= N_EDGES) return;
    const float4* ea = (const float4*)(edge_attr + (size_t)e * 16);
    const float4* wf = (const float4*)w_fc1;
    float acc = b_fc1[0];
#pragma unroll
    for (int i = 0; i < 4; i++) {
        float4 a = ea[i], w = wf[i];
        acc += a.x * w.x + a.y * w.y + a.z * w.z + a.w * w.w;
    }
    ew[e] = acc;
    int dst = edge_index[N_EDGES + e];
    dst16[e] = (u16)dst;
    atomicAdd(&deg[dst], 1);
}

// ---------------------------------------------------------------------------
// Hierarchical exclusive scan of deg[N] -> rowptr[N+1], cursor[N]
// ---------------------------------------------------------------------------
__global__ __launch_bounds__(256) void scan1_kernel(const int* __restrict__ deg,
                                                    int* __restrict__ rowptr,
                                                    int* __restrict__ blk_sums) {
    __shared__ int sh[256];
    const int t = threadIdx.x;
    const int base = blockIdx.x * 512;
    const int i0 = base + 2 * t, i1 = i0 + 1;
    const int d0 = (i0 < N_NODES) ? deg[i0] : 0;
    const int d1 = (i1 < N_NODES) ? deg[i1] : 0;
    const int pair = d0 + d1;
    int v = pair;
    sh[t] = v;
    __syncthreads();
#pragma unroll
    for (int off = 1; off < 256; off <<= 1) {
        int add = (t >= off) ? sh[t - off] : 0;
        __syncthreads();
        v += add;
        sh[t] = v;
        __syncthreads();
    }
    const int excl = v - pair;
    if (i0 < N_NODES) rowptr[i0] = excl;
    if (i1 < N_NODES) rowptr[i1] = excl + d0;
    if (t == 255) blk_sums[blockIdx.x] = v;
}

__global__ __launch_bounds__(128) void scan2_kernel(const int* __restrict__ blk_sums,
                                                    int* __restrict__ blk_offs,
                                                    int* __restrict__ rowptr) {
    __shared__ int sh[128];
    const int t = threadIdx.x;
    const int orig = (t < SCAN_NB) ? blk_sums[t] : 0;
    int v = orig;
    sh[t] = v;
    __syncthreads();
#pragma unroll
    for (int off = 1; off < 128; off <<= 1) {
        int add = (t >= off) ? sh[t - off] : 0;
        __syncthreads();
        v += add;
        sh[t] = v;
        __syncthreads();
    }
    if (t < SCAN_NB) blk_offs[t] = v - orig;
    if (t == 127) rowptr[N_NODES] = v;
}

__global__ void scan3_kernel(int* __restrict__ rowptr,
                             const int* __restrict__ blk_offs,
                             int* __restrict__ cursor) {
    int i = blockIdx.x * blockDim.x + threadIdx.x;
    if (i >= N_NODES) return;
    int r = rowptr[i] + blk_offs[i >> 9];
    rowptr[i] = r;
    cursor[i] = r;
}

// ---------------------------------------------------------------------------
// CSR placement, dst-range partitioned for write locality.
// pass = blockIdx.x & 7 (XCD round-robin heuristic): pass k handles only
// dst in [k*6250, (k+1)*6250) -> its csr write region is ~800KB and all its
// writer blocks co-locate on one XCD L2 -> lines fill before eviction.
// ---------------------------------------------------------------------------
__global__ __launch_bounds__(256) void place_kernel(const int* __restrict__ edge_index,
                                                    const float* __restrict__ ew,
                                                    const u16* __restrict__ dst16,
                                                    int* __restrict__ cursor,
                                                    int2* __restrict__ csr) {
    const int pass = blockIdx.x & (NPASS - 1);
    const int chunk = blockIdx.x >> 3;
    const int lo = pass * NODES_PER_PASS;
    const int hi = lo + NODES_PER_PASS;
    const int base = chunk * 1024 + threadIdx.x;
#pragma unroll
    for (int u = 0; u < 4; u++) {
        const int e = base + u * 256;
        if (e >= N_EDGES) break;
        const int d = (int)dst16[e];
        if (d >= lo && d < hi) {
            int pos = atomicAdd(&cursor[d], 1);
            int2 ent;
            ent.x = edge_index[e];
            ent.y = __float_as_int(ew[e]);
            csr[pos] = ent;
        }
    }
}

// ---------------------------------------------------------------------------
// Gather aggregation (bf16 in/out, fp32 accumulate), one WAVE per node.
// Also writes ch[node] = c[node] * xin[node] (bf16) — the gemm's region 2.
// Layer 0 (WRITE_C) computes c[node] = sum of row weights and stores it.
// ---------------------------------------------------------------------------
template <int DIN, bool WRITE_C>
__global__ __launch_bounds__(256) void gather_kernel(
    const u16* __restrict__ xb, const int* __restrict__ rowptr,
    const int2* __restrict__ csr, u16* __restrict__ sb,
    u16* __restrict__ chb, float* __restrict__ c) {
    constexpr int CG = DIN / 4;   // uint2 (4 bf16) groups per row: 16 or 32
    constexpr int EG = 64 / CG;   // edge groups: 4 or 2
    const int gid = blockIdx.x * 256 + threadIdx.x;
    const int node = gid >> 6;
    if (node >= N_NODES) return;
    const int lane = threadIdx.x & 63;
    const int cg = lane & (CG - 1);
    const int eg = lane / CG;
    const int beg = rowptr[node];
    const int end = rowptr[node + 1];
    const uint2* x2 = (const uint2*)xb;

    float a0 = 0.f, a1 = 0.f, a2 = 0.f, a3 = 0.f;
    float b0 = 0.f, b1 = 0.f, b2 = 0.f, b3 = 0.f;
    float wsum = 0.f;

    int p = beg + eg;
    for (; p + EG < end; p += 2 * EG) {
        int2 e0 = csr[p];
        int2 e1 = csr[p + EG];
        float w0 = __int_as_float(e0.y);
        float w1 = __int_as_float(e1.y);
        uint2 v0 = x2[(size_t)e0.x * CG + cg];
        uint2 v1 = x2[(size_t)e1.x * CG + cg];
        float f0, f1, f2, f3, g0, g1, g2, g3;
        bfpair(v0.x, f0, f1); bfpair(v0.y, f2, f3);
        bfpair(v1.x, g0, g1); bfpair(v1.y, g2, g3);
        a0 += w0 * f0; a1 += w0 * f1; a2 += w0 * f2; a3 += w0 * f3;
        b0 += w1 * g0; b1 += w1 * g1; b2 += w1 * g2; b3 += w1 * g3;
        wsum += w0 + w1;
    }
    if (p < end) {
        int2 e0 = csr[p];
        float w0 = __int_as_float(e0.y);
        uint2 v0 = x2[(size_t)e0.x * CG + cg];
        float f0, f1, f2, f3;
        bfpair(v0.x, f0, f1); bfpair(v0.y, f2, f3);
        a0 += w0 * f0; a1 += w0 * f1; a2 += w0 * f2; a3 += w0 * f3;
        wsum += w0;
    }
    a0 += b0; a1 += b1; a2 += b2; a3 += b3;

#pragma unroll
    for (int off = 32; off >= CG; off >>= 1) {
        a0 += __shfl_xor(a0, off);
        a1 += __shfl_xor(a1, off);
        a2 += __shfl_xor(a2, off);
        a3 += __shfl_xor(a3, off);
        wsum += __shfl_xor(wsum, off);
    }

    if (lane < CG) {
        uint2 so;
        so.x = packbf(a0, a1);
        so.y = packbf(a2, a3);
        ((uint2*)sb)[(size_t)node * CG + cg] = so;
        const float cn = WRITE_C ? wsum : c[node];
        uint2 hv = x2[(size_t)node * CG + cg];
        float h0, h1, h2, h3;
        bfpair(hv.x, h0, h1); bfpair(hv.y, h2, h3);
        uint2 co;
        co.x = packbf(cn * h0, cn * h1);
        co.y = packbf(cn * h2, cn * h3);
        ((uint2*)chb)[(size_t)node * CG + cg] = co;
    }
    if (WRITE_C && lane == 0) c[node] = wsum;
}

// ---------------------------------------------------------------------------
// Pack weights [w3 ; w1 ; -w2] into MFMA B-frag layout (bf16).
// ---------------------------------------------------------------------------
__global__ void pack_w_kernel(const float* __restrict__ w3_0, const float* __restrict__ w1_0, const float* __restrict__ w2_0,
                              const float* __restrict__ w3_1, const float* __restrict__ w1_1, const float* __restrict__ w2_1,
                              const float* __restrict__ w3_2, const float* __restrict__ w1_2, const float* __restrict__ w2_2,
                              u16* __restrict__ bp0, u16* __restrict__ bp1, u16* __restrict__ bp2) {
    int t = blockIdx.x * blockDim.x + threadIdx.x;
    if (t >= 7680) return;
    int DIN, DOUT, lid;
    const float *w3, *w1, *w2;
    u16* bp;
    if (t < 1536)      { DIN = 64;  DOUT = 64;  lid = t;        w3 = w3_0; w1 = w1_0; w2 = w2_0; bp = bp0; }
    else if (t < 4608) { DIN = 64;  DOUT = 128; lid = t - 1536; w3 = w3_1; w1 = w1_1; w2 = w2_1; bp = bp1; }
    else               { DIN = 128; DOUT = 64;  lid = t - 4608; w3 = w3_2; w1 = w1_2; w2 = w2_2; bp = bp2; }
    const int NT = DOUT / 16;
    const int lane = lid & 63;
    const int fragid = lid >> 6;
    const int chunk = fragid / NT;
    const int ntile = fragid % NT;
    const int n = ntile * 16 + (lane & 15);
    const int kbase = chunk * 32 + (lane >> 4) * 8;
    u16 buf[8];
#pragma unroll
    for (int j = 0; j < 8; j++) {
        int k = kbase + j;
        int region = k / DIN;
        int kk = k - region * DIN;
        float v = (region == 0) ? w3[kk * DOUT + n]
                : (region == 1) ? w1[kk * DOUT + n]
                                : -w2[kk * DOUT + n];
        buf[j] = f2bf(v);
    }
    *(bf16x8*)(bp + ((size_t)lid << 3)) = *(bf16x8*)buf;
}

// ---------------------------------------------------------------------------
// MFMA GEMM: out = elu( [h | s | ch] @ Bp + b3 + c*b1 ),  bf16 in, fp32 acc.
// ---------------------------------------------------------------------------
template <int DIN, int DOUT>
__global__ __launch_bounds__(256) void gemm_mfma(
    const u16* __restrict__ hb, const u16* __restrict__ sb,
    const u16* __restrict__ chb, const u16* __restrict__ Bp,
    const float* __restrict__ cvec, const float* __restrict__ bias1,
    const float* __restrict__ bias3, u16* __restrict__ outp) {
    constexpr int CH = DIN / 32;
    constexpr int CHUNKS = 3 * CH;
    constexpr int NT = DOUT / 16;
    const int tid = threadIdx.x;
    const int wv = tid >> 6;
    const int lane = tid & 63;
    const int l15 = lane & 15;
    const int q = lane >> 4;
    const int mhalf = wv & 1;
    const int nhalf = wv >> 1;
    const int row_base = blockIdx.x * 64 + mhalf * 32;
    const int nt0 = blockIdx.y * 4 + nhalf * 2;

    const int r0 = min(row_base + l15, N_NODES - 1);
    const int r1 = min(row_base + 16 + l15, N_NODES - 1);
    const int qo = q * 8;

    f32x4 acc00 = {0.f, 0.f, 0.f, 0.f};
    f32x4 acc01 = {0.f, 0.f, 0.f, 0.f};
    f32x4 acc10 = {0.f, 0.f, 0.f, 0.f};
    f32x4 acc11 = {0.f, 0.f, 0.f, 0.f};

#pragma unroll
    for (int chunk = 0; chunk < CHUNKS; chunk++) {
        const int region = chunk / CH;
        const int koff = (chunk - region * CH) * 32 + qo;
        const u16* A = (region == 0) ? hb : (region == 1) ? sb : chb;
        bf16x8 a0 = *(const bf16x8*)(A + (size_t)r0 * DIN + koff);
        bf16x8 a1 = *(const bf16x8*)(A + (size_t)r1 * DIN + koff);
        const u16* bp = Bp + (((size_t)(chunk * NT + nt0) * 64 + lane) << 3);
        bf16x8 bf0 = *(const bf16x8*)bp;
        bf16x8 bf1 = *(const bf16x8*)(bp + 64 * 8);
        acc00 = __builtin_amdgcn_mfma_f32_16x16x32_bf16(a0, bf0, acc00, 0, 0, 0);
        acc01 = __builtin_amdgcn_mfma_f32_16x16x32_bf16(a0, bf1, acc01, 0, 0, 0);
        acc10 = __builtin_amdgcn_mfma_f32_16x16x32_bf16(a1, bf0, acc10, 0, 0, 0);
        acc11 = __builtin_amdgcn_mfma_f32_16x16x32_bf16(a1, bf1, acc11, 0, 0, 0);
    }

#pragma unroll
    for (int ni = 0; ni < 2; ni++) {
        const int col = (nt0 + ni) * 16 + l15;
        const float B3 = bias3[col];
        const float B1 = bias1[col];
        const f32x4 am0 = ni ? acc01 : acc00;
        const f32x4 am1 = ni ? acc11 : acc10;
#pragma unroll
        for (int mi = 0; mi < 2; mi++) {
            const f32x4 av = mi ? am1 : am0;
#pragma unroll
            for (int reg = 0; reg < 4; reg++) {
                const int row = row_base + mi * 16 + q * 4 + reg;
                if (row < N_NODES) {
                    const float cv = cvec[row];
                    const float val = av[reg] + B3 + cv * B1;
                    outp[(size_t)row * DOUT + col] = f2bf(elu_f(val));
                }
            }
        }
    }
}

// ---------------------------------------------------------------------------
// out[g, :] = max over nodes of graph g of h[:, :64] (bf16 in, fp32 out)
// ---------------------------------------------------------------------------
__global__ void pool_kernel(const u16* __restrict__ h,
                            const int* __restrict__ batch,
                            float* __restrict__ out) {
    const int g = blockIdx.x;
    const int tid = threadIdx.x;
    int lo = 0, hi = N_NODES;
    while (lo < hi) { int mid = (lo + hi) >> 1; if (batch[mid] < g) lo = mid + 1; else hi = mid; }
    const int beg = lo;
    lo = beg; hi = N_NODES;
    while (lo < hi) { int mid = (lo + hi) >> 1; if (batch[mid] < g + 1) lo = mid + 1; else hi = mid; }
    const int end = lo;

    __shared__ float red[256];
    const int col = tid & 63;
    const int rg = tid >> 6;
    float m = -3.0e38f;
    for (int r = beg + rg; r < end; r += 4) m = fmaxf(m, bf2f(h[(size_t)r * 64 + col]));
    red[tid] = m;
    __syncthreads();
    if (tid < 64) {
        m = fmaxf(fmaxf(red[tid], red[tid + 64]), fmaxf(red[tid + 128], red[tid + 192]));
        out[g * 64 + tid] = m;
    }
}

extern "C" void kernel_launch(void* const* d_in, const int* in_sizes, int n_in,
                              void* d_out, int out_size, void* d_ws, size_t ws_size,
                              hipStream_t stream) {
    const float* x = (const float*)d_in[0];
    const int* ei = (const int*)d_in[1];
    const float* ea = (const float*)d_in[2];
    const int* batch = (const int*)d_in[3];
    const float* wfc = (const float*)d_in[4];
    const float* bfc = (const float*)d_in[5];
    const float* w1_0 = (const float*)d_in[6];
    const float* b1_0 = (const float*)d_in[7];
    const float* w2_0 = (const float*)d_in[8];
    const float* w3_0 = (const float*)d_in[9];
    const float* b3_0 = (const float*)d_in[10];
    const float* w1_1 = (const float*)d_in[11];
    const float* b1_1 = (const float*)d_in[12];
    const float* w2_1 = (const float*)d_in[13];
    const float* w3_1 = (const float*)d_in[14];
    const float* b3_1 = (const float*)d_in[15];
    const float* w1_2 = (const float*)d_in[16];
    const float* b1_2 = (const float*)d_in[17];
    const float* w2_2 = (const float*)d_in[18];
    const float* w3_2 = (const float*)d_in[19];
    const float* b3_2 = (const float*)d_in[20];
    float* out = (float*)d_out;

    char* ws = (char*)d_ws;
    float* ew      = (float*)(ws);                 // E f32      3.2 MB
    float* c       = (float*)(ws + 3200000);       // N f32
    int*   deg     = (int*)  (ws + 3400000);       // N int
    int*   cursor  = (int*)  (ws + 3600000);       // N int
    int*   rowptr  = (int*)  (ws + 3800000);       // N+1 int
    int2*  csr     = (int2*) (ws + 4000128);       // E int2     6.4 MB
    u16*   xb      = (u16*)  (ws + 10400128);      // N*64 bf16  6.4 MB
    u16*   sb      = (u16*)  (ws + 16800128);      // N*128 bf16 12.8 MB
    u16*   chb     = (u16*)  (ws + 29600128);      // N*128 bf16 12.8 MB (reused per layer)
    u16*   h1      = (u16*)  (ws + 42400128);      // N*64 bf16  6.4 MB
    u16*   h2      = (u16*)  (ws + 48800128);      // N*128 bf16 12.8 MB
    u16*   h3      = (u16*)  (ws + 61600128);      // N*64 bf16  6.4 MB
    u16*   bp0     = (u16*)  (ws + 68000128);      // 24 KB packed weights L0
    u16*   bp1     = (u16*)  (ws + 68024704);      // 48 KB L1
    u16*   bp2     = (u16*)  (ws + 68073856);      // 48 KB L2
    int* blk_sums  = (int*)  (ws + 68123008);
    int* blk_offs  = (int*)  (ws + 68123520);
    // dst16 aliases chb: place finishes before gather-0 writes chb
    u16* dst16 = chb;

    hipMemsetAsync(deg, 0, N_NODES * sizeof(int), stream);

    conv_x_kernel<<<3125, 256, 0, stream>>>(x, xb);
    ew_deg_kernel<<<(N_EDGES + 255) / 256, 256, 0, stream>>>(ea, wfc, bfc, ei, ew, dst16, deg);
    pack_w_kernel<<<30, 256, 0, stream>>>(w3_0, w1_0, w2_0, w3_1, w1_1, w2_1,
                                          w3_2, w1_2, w2_2, bp0, bp1, bp2);
    scan1_kernel<<<SCAN_NB, 256, 0, stream>>>(deg, rowptr, blk_sums);
    scan2_kernel<<<1, 128, 0, stream>>>(blk_sums, blk_offs, rowptr);
    scan3_kernel<<<(N_NODES + 255) / 256, 256, 0, stream>>>(rowptr, blk_offs, cursor);
    // 782 chunks x 8 passes, pass = blockIdx & 7 (XCD swizzle)
    place_kernel<<<782 * NPASS, 256, 0, stream>>>(ei, ew, dst16, cursor, csr);

    const int RB = (N_NODES + 63) / 64;           // 782 row-blocks
    const int GBLK = (N_NODES * 64 + 255) / 256;  // one wave per node

    // layer 0: 64 -> 64
    gather_kernel<64, true><<<GBLK, 256, 0, stream>>>(xb, rowptr, csr, sb, chb, c);
    gemm_mfma<64, 64><<<dim3(RB, 1), 256, 0, stream>>>(xb, sb, chb, bp0, c, b1_0, b3_0, h1);

    // layer 1: 64 -> 128
    gather_kernel<64, false><<<GBLK, 256, 0, stream>>>(h1, rowptr, csr, sb, chb, c);
    gemm_mfma<64, 128><<<dim3(RB, 2), 256, 0, stream>>>(h1, sb, chb, bp1, c, b1_1, b3_1, h2);

    // layer 2: 128 -> 64
    gather_kernel<128, false><<<GBLK, 256, 0, stream>>>(h2, rowptr, csr, sb, chb, c);
    gemm_mfma<128, 64><<<dim3(RB, 1), 256, 0, stream>>>(h2, sb, chb, bp2, c, b1_2, b3_2, h3);

    // global max pool
    pool_kernel<<<NUM_GRAPHS_, 256, 0, stream>>>(h3, batch, out);
}

// Round 9
// 369.841 us; speedup vs baseline: 1.3261x; 1.0366x over previous
//
#include <hip/hip_runtime.h>
#include <math.h>

#define N_NODES 50000
#define N_EDGES 800000
#define NUM_GRAPHS_ 128
#define SCAN_NB 98   // ceil(50000/512)
#define NPASS 8
#define NODES_PER_PASS 6250  // 50000/8
#define HCHUNKS 128
#define EDGES_PER_CHUNK 6250 // 800000/128
#define HWORDS 12500         // 25000 nodes per half, 2 per word

typedef unsigned short u16;
typedef unsigned int u32;
typedef __attribute__((ext_vector_type(8))) short bf16x8;   // 8 bf16 (4 VGPRs)
typedef __attribute__((ext_vector_type(4))) float f32x4;    // 4 fp32

__device__ __forceinline__ float elu_f(float v) {
    return v > 0.f ? v : (__expf(v) - 1.f);
}
__device__ __forceinline__ u16 f2bf(float f) {  // RNE
    u32 u = __float_as_uint(f);
    u += 0x7FFFu + ((u >> 16) & 1u);
    return (u16)(u >> 16);
}
__device__ __forceinline__ float bf2f(u16 h) {
    return __uint_as_float(((u32)h) << 16);
}
__device__ __forceinline__ void bfpair(u32 v, float& lo, float& hi) {
    lo = __uint_as_float(v << 16);
    hi = __uint_as_float(v & 0xFFFF0000u);
}
__device__ __forceinline__ u32 packbf(float lo, float hi) {
    return (u32)f2bf(lo) | ((u32)f2bf(hi) << 16);
}

// ---------------------------------------------------------------------------
// xb = bf16(x), N*64 elements, 4 per thread
// ---------------------------------------------------------------------------
__global__ void conv_x_kernel(const float* __restrict__ x, u16* __restrict__ xb) {
    int g = blockIdx.x * blockDim.x + threadIdx.x;
    float4 v = ((const float4*)x)[g];
    uint2 o;
    o.x = packbf(v.x, v.y);
    o.y = packbf(v.z, v.w);
    ((uint2*)xb)[g] = o;
}

// ---------------------------------------------------------------------------
// ew[e] = edge_attr[e,:16] . w_fc1 + b_fc1 ; dst16[e] = dst.  NO atomics.
// ---------------------------------------------------------------------------
__global__ void ew_kernel(const float* __restrict__ edge_attr,
                          const float* __restrict__ w_fc1,
                          const float* __restrict__ b_fc1,
                          const int* __restrict__ edge_index,
                          float* __restrict__ ew,
                          u16* __restrict__ dst16) {
    int e = blockIdx.x * blockDim.x + threadIdx.x;
    if (e >= N_EDGES) return;
    const float4* ea = (const float4*)(edge_attr + (size_t)e * 16);
    const float4* wf = (const float4*)w_fc1;
    float acc = b_fc1[0];
#pragma unroll
    for (int i = 0; i < 4; i++) {
        float4 a = ea[i], w = wf[i];
        acc += a.x * w.x + a.y * w.y + a.z * w.z + a.w * w.w;
    }
    ew[e] = acc;
    dst16[e] = (u16)edge_index[N_EDGES + e];
}

// ---------------------------------------------------------------------------
// Degree histogram, NO global atomics. Block (chunk c, half p): LDS-histogram
// chunk's edges whose dst is in half p (packed u16 pairs, LDS atomics only),
// then write the 50KB partial densely (coalesced full lines).
// ---------------------------------------------------------------------------
__global__ __launch_bounds__(256) void deg_hist_kernel(const u16* __restrict__ dst16,
                                                       u32* __restrict__ partial) {
    __shared__ u32 bins[HWORDS];
    const int c = blockIdx.x >> 1;
    const int p = blockIdx.x & 1;
    const int t = threadIdx.x;
    for (int i = t; i < HWORDS; i += 256) bins[i] = 0;
    __syncthreads();
    const int base = c * EDGES_PER_CHUNK;
    const int nlo = p * 25000;
    for (int i = t; i < EDGES_PER_CHUNK; i += 256) {
        const int b = (int)dst16[base + i] - nlo;
        if ((unsigned)b < 25000u)
            atomicAdd(&bins[b >> 1], 1u << ((b & 1) * 16));
    }
    __syncthreads();
    u32* outp = partial + (size_t)blockIdx.x * HWORDS;
    for (int i = t; i < HWORDS; i += 256) outp[i] = bins[i];
}

// ---------------------------------------------------------------------------
// Reduce partials -> deg4[y][N] (y sums chunks y*32..y*32+31); scan1 sums y.
// ---------------------------------------------------------------------------
__global__ void deg_reduce_kernel(const u32* __restrict__ partial,
                                  u32* __restrict__ deg4) {
    const int tidg = blockIdx.x * 256 + threadIdx.x;  // 25000 slots
    if (tidg >= 25000) return;
    const int p = (tidg >= HWORDS) ? 1 : 0;
    const int w = tidg - p * HWORDS;
    const int y = blockIdx.y;  // 0..3
    u32 lo = 0, hi = 0;
#pragma unroll 8
    for (int j = 0; j < 32; j++) {
        u32 v = partial[(size_t)(((y * 32 + j) << 1) + p) * HWORDS + w];
        lo += v & 0xFFFFu;
        hi += v >> 16;
    }
    const int n = p * 25000 + 2 * w;
    deg4[(size_t)y * N_NODES + n] = lo;
    deg4[(size_t)y * N_NODES + n + 1] = hi;
}

// ---------------------------------------------------------------------------
// Hierarchical exclusive scan of deg4 -> rowptr[N+1], cursor[N]
// ---------------------------------------------------------------------------
__global__ __launch_bounds__(256) void scan1_kernel(const u32* __restrict__ deg4,
                                                    int* __restrict__ rowptr,
                                                    int* __restrict__ blk_sums) {
    __shared__ int sh[256];
    const int t = threadIdx.x;
    const int base = blockIdx.x * 512;
    const int i0 = base + 2 * t, i1 = i0 + 1;
    int d0 = 0, d1 = 0;
    if (i0 < N_NODES) {
#pragma unroll
        for (int y = 0; y < 4; y++) {
            d0 += (int)deg4[(size_t)y * N_NODES + i0];
            d1 += (int)deg4[(size_t)y * N_NODES + i1];
        }
    }
    const int pair = d0 + d1;
    int v = pair;
    sh[t] = v;
    __syncthreads();
#pragma unroll
    for (int off = 1; off < 256; off <<= 1) {
        int add = (t >= off) ? sh[t - off] : 0;
        __syncthreads();
        v += add;
        sh[t] = v;
        __syncthreads();
    }
    const int excl = v - pair;
    if (i0 < N_NODES) rowptr[i0] = excl;
    if (i1 < N_NODES) rowptr[i1] = excl + d0;
    if (t == 255) blk_sums[blockIdx.x] = v;
}

__global__ __launch_bounds__(128) void scan2_kernel(const int* __restrict__ blk_sums,
                                                    int* __restrict__ blk_offs,
                                                    int* __restrict__ rowptr) {
    __shared__ int sh[128];
    const int t = threadIdx.x;
    const int orig = (t < SCAN_NB) ? blk_sums[t] : 0;
    int v = orig;
    sh[t] = v;
    __syncthreads();
#pragma unroll
    for (int off = 1; off < 128; off <<= 1) {
        int add = (t >= off) ? sh[t - off] : 0;
        __syncthreads();
        v += add;
        sh[t] = v;
        __syncthreads();
    }
    if (t < SCAN_NB) blk_offs[t] = v - orig;
    if (t == 127) rowptr[N_NODES] = v;
}

__global__ void scan3_kernel(int* __restrict__ rowptr,
                             const int* __restrict__ blk_offs,
                             int* __restrict__ cursor) {
    int i = blockIdx.x * blockDim.x + threadIdx.x;
    if (i >= N_NODES) return;
    int r = rowptr[i] + blk_offs[i >> 9];
    rowptr[i] = r;
    cursor[i] = r;
}

// ---------------------------------------------------------------------------
// CSR placement, dst-range partitioned for write locality (8 passes).
// ---------------------------------------------------------------------------
__global__ __launch_bounds__(256) void place_kernel(const int* __restrict__ edge_index,
                                                    const float* __restrict__ ew,
                                                    const u16* __restrict__ dst16,
                                                    int* __restrict__ cursor,
                                                    int2* __restrict__ csr) {
    const int pass = blockIdx.x & (NPASS - 1);
    const int chunk = blockIdx.x >> 3;
    const int lo = pass * NODES_PER_PASS;
    const int hi = lo + NODES_PER_PASS;
    const int base = chunk * 1024 + threadIdx.x;
#pragma unroll
    for (int u = 0; u < 4; u++) {
        const int e = base + u * 256;
        if (e >= N_EDGES) break;
        const int d = (int)dst16[e];
        if (d >= lo && d < hi) {
            int pos = atomicAdd(&cursor[d], 1);
            int2 ent;
            ent.x = edge_index[e];
            ent.y = __float_as_int(ew[e]);
            csr[pos] = ent;
        }
    }
}

// ---------------------------------------------------------------------------
// Gather aggregation (bf16 in/out, fp32 accumulate), one WAVE per node.
// Also writes ch[node] = c[node] * xin[node] (bf16). Layer 0 emits c.
// ---------------------------------------------------------------------------
template <int DIN, bool WRITE_C>
__global__ __launch_bounds__(256) void gather_kernel(
    const u16* __restrict__ xb, const int* __restrict__ rowptr,
    const int2* __restrict__ csr, u16* __restrict__ sb,
    u16* __restrict__ chb, float* __restrict__ c) {
    constexpr int CG = DIN / 4;   // uint2 (4 bf16) groups per row: 16 or 32
    constexpr int EG = 64 / CG;   // edge groups: 4 or 2
    const int gid = blockIdx.x * 256 + threadIdx.x;
    const int node = gid >> 6;
    if (node >= N_NODES) return;
    const int lane = threadIdx.x & 63;
    const int cg = lane & (CG - 1);
    const int eg = lane / CG;
    const int beg = rowptr[node];
    const int end = rowptr[node + 1];
    const uint2* x2 = (const uint2*)xb;

    float a0 = 0.f, a1 = 0.f, a2 = 0.f, a3 = 0.f;
    float b0 = 0.f, b1 = 0.f, b2 = 0.f, b3 = 0.f;
    float wsum = 0.f;

    int p = beg + eg;
    for (; p + EG < end; p += 2 * EG) {
        int2 e0 = csr[p];
        int2 e1 = csr[p + EG];
        float w0 = __int_as_float(e0.y);
        float w1 = __int_as_float(e1.y);
        uint2 v0 = x2[(size_t)e0.x * CG + cg];
        uint2 v1 = x2[(size_t)e1.x * CG + cg];
        float f0, f1, f2, f3, g0, g1, g2, g3;
        bfpair(v0.x, f0, f1); bfpair(v0.y, f2, f3);
        bfpair(v1.x, g0, g1); bfpair(v1.y, g2, g3);
        a0 += w0 * f0; a1 += w0 * f1; a2 += w0 * f2; a3 += w0 * f3;
        b0 += w1 * g0; b1 += w1 * g1; b2 += w1 * g2; b3 += w1 * g3;
        wsum += w0 + w1;
    }
    if (p < end) {
        int2 e0 = csr[p];
        float w0 = __int_as_float(e0.y);
        uint2 v0 = x2[(size_t)e0.x * CG + cg];
        float f0, f1, f2, f3;
        bfpair(v0.x, f0, f1); bfpair(v0.y, f2, f3);
        a0 += w0 * f0; a1 += w0 * f1; a2 += w0 * f2; a3 += w0 * f3;
        wsum += w0;
    }
    a0 += b0; a1 += b1; a2 += b2; a3 += b3;

#pragma unroll
    for (int off = 32; off >= CG; off >>= 1) {
        a0 += __shfl_xor(a0, off);
        a1 += __shfl_xor(a1, off);
        a2 += __shfl_xor(a2, off);
        a3 += __shfl_xor(a3, off);
        wsum += __shfl_xor(wsum, off);
    }

    if (lane < CG) {
        uint2 so;
        so.x = packbf(a0, a1);
        so.y = packbf(a2, a3);
        ((uint2*)sb)[(size_t)node * CG + cg] = so;
        const float cn = WRITE_C ? wsum : c[node];
        uint2 hv = x2[(size_t)node * CG + cg];
        float h0, h1, h2, h3;
        bfpair(hv.x, h0, h1); bfpair(hv.y, h2, h3);
        uint2 co;
        co.x = packbf(cn * h0, cn * h1);
        co.y = packbf(cn * h2, cn * h3);
        ((uint2*)chb)[(size_t)node * CG + cg] = co;
    }
    if (WRITE_C && lane == 0) c[node] = wsum;
}

// ---------------------------------------------------------------------------
// Pack weights [w3 ; w1 ; -w2] into MFMA B-frag layout (bf16).
// ---------------------------------------------------------------------------
__global__ void pack_w_kernel(const float* __restrict__ w3_0, const float* __restrict__ w1_0, const float* __restrict__ w2_0,
                              const float* __restrict__ w3_1, const float* __restrict__ w1_1, const float* __restrict__ w2_1,
                              const float* __restrict__ w3_2, const float* __restrict__ w1_2, const float* __restrict__ w2_2,
                              u16* __restrict__ bp0, u16* __restrict__ bp1, u16* __restrict__ bp2) {
    int t = blockIdx.x * blockDim.x + threadIdx.x;
    if (t >= 7680) return;
    int DIN, DOUT, lid;
    const float *w3, *w1, *w2;
    u16* bp;
    if (t < 1536)      { DIN = 64;  DOUT = 64;  lid = t;        w3 = w3_0; w1 = w1_0; w2 = w2_0; bp = bp0; }
    else if (t < 4608) { DIN = 64;  DOUT = 128; lid = t - 1536; w3 = w3_1; w1 = w1_1; w2 = w2_1; bp = bp1; }
    else               { DIN = 128; DOUT = 64;  lid = t - 4608; w3 = w3_2; w1 = w1_2; w2 = w2_2; bp = bp2; }
    const int NT = DOUT / 16;
    const int lane = lid & 63;
    const int fragid = lid >> 6;
    const int chunk = fragid / NT;
    const int ntile = fragid % NT;
    const int n = ntile * 16 + (lane & 15);
    const int kbase = chunk * 32 + (lane >> 4) * 8;
    u16 buf[8];
#pragma unroll
    for (int j = 0; j < 8; j++) {
        int k = kbase + j;
        int region = k / DIN;
        int kk = k - region * DIN;
        float v = (region == 0) ? w3[kk * DOUT + n]
                : (region == 1) ? w1[kk * DOUT + n]
                                : -w2[kk * DOUT + n];
        buf[j] = f2bf(v);
    }
    *(bf16x8*)(bp + ((size_t)lid << 3)) = *(bf16x8*)buf;
}

// ---------------------------------------------------------------------------
// MFMA GEMM: out = elu( [h | s | ch] @ Bp + b3 + c*b1 ),  bf16 in, fp32 acc.
// ---------------------------------------------------------------------------
template <int DIN, int DOUT>
__global__ __launch_bounds__(256) void gemm_mfma(
    const u16* __restrict__ hb, const u16* __restrict__ sb,
    const u16* __restrict__ chb, const u16* __restrict__ Bp,
    const float* __restrict__ cvec, const float* __restrict__ bias1,
    const float* __restrict__ bias3, u16* __restrict__ outp) {
    constexpr int CH = DIN / 32;
    constexpr int CHUNKS = 3 * CH;
    constexpr int NT = DOUT / 16;
    const int tid = threadIdx.x;
    const int wv = tid >> 6;
    const int lane = tid & 63;
    const int l15 = lane & 15;
    const int q = lane >> 4;
    const int mhalf = wv & 1;
    const int nhalf = wv >> 1;
    const int row_base = blockIdx.x * 64 + mhalf * 32;
    const int nt0 = blockIdx.y * 4 + nhalf * 2;

    const int r0 = min(row_base + l15, N_NODES - 1);
    const int r1 = min(row_base + 16 + l15, N_NODES - 1);
    const int qo = q * 8;

    f32x4 acc00 = {0.f, 0.f, 0.f, 0.f};
    f32x4 acc01 = {0.f, 0.f, 0.f, 0.f};
    f32x4 acc10 = {0.f, 0.f, 0.f, 0.f};
    f32x4 acc11 = {0.f, 0.f, 0.f, 0.f};

#pragma unroll
    for (int chunk = 0; chunk < CHUNKS; chunk++) {
        const int region = chunk / CH;
        const int koff = (chunk - region * CH) * 32 + qo;
        const u16* A = (region == 0) ? hb : (region == 1) ? sb : chb;
        bf16x8 a0 = *(const bf16x8*)(A + (size_t)r0 * DIN + koff);
        bf16x8 a1 = *(const bf16x8*)(A + (size_t)r1 * DIN + koff);
        const u16* bp = Bp + (((size_t)(chunk * NT + nt0) * 64 + lane) << 3);
        bf16x8 bf0 = *(const bf16x8*)bp;
        bf16x8 bf1 = *(const bf16x8*)(bp + 64 * 8);
        acc00 = __builtin_amdgcn_mfma_f32_16x16x32_bf16(a0, bf0, acc00, 0, 0, 0);
        acc01 = __builtin_amdgcn_mfma_f32_16x16x32_bf16(a0, bf1, acc01, 0, 0, 0);
        acc10 = __builtin_amdgcn_mfma_f32_16x16x32_bf16(a1, bf0, acc10, 0, 0, 0);
        acc11 = __builtin_amdgcn_mfma_f32_16x16x32_bf16(a1, bf1, acc11, 0, 0, 0);
    }

#pragma unroll
    for (int ni = 0; ni < 2; ni++) {
        const int col = (nt0 + ni) * 16 + l15;
        const float B3 = bias3[col];
        const float B1 = bias1[col];
        const f32x4 am0 = ni ? acc01 : acc00;
        const f32x4 am1 = ni ? acc11 : acc10;
#pragma unroll
        for (int mi = 0; mi < 2; mi++) {
            const f32x4 av = mi ? am1 : am0;
#pragma unroll
            for (int reg = 0; reg < 4; reg++) {
                const int row = row_base + mi * 16 + q * 4 + reg;
                if (row < N_NODES) {
                    const float cv = cvec[row];
                    const float val = av[reg] + B3 + cv * B1;
                    outp[(size_t)row * DOUT + col] = f2bf(elu_f(val));
                }
            }
        }
    }
}

// ---------------------------------------------------------------------------
// out[g, :] = max over nodes of graph g of h[:, :64] (bf16 in, fp32 out)
// ---------------------------------------------------------------------------
__global__ void pool_kernel(const u16* __restrict__ h,
                            const int* __restrict__ batch,
                            float* __restrict__ out) {
    const int g = blockIdx.x;
    const int tid = threadIdx.x;
    int lo = 0, hi = N_NODES;
    while (lo < hi) { int mid = (lo + hi) >> 1; if (batch[mid] < g) lo = mid + 1; else hi = mid; }
    const int beg = lo;
    lo = beg; hi = N_NODES;
    while (lo < hi) { int mid = (lo + hi) >> 1; if (batch[mid] < g + 1) lo = mid + 1; else hi = mid; }
    const int end = lo;

    __shared__ float red[256];
    const int col = tid & 63;
    const int rg = tid >> 6;
    float m = -3.0e38f;
    for (int r = beg + rg; r < end; r += 4) m = fmaxf(m, bf2f(h[(size_t)r * 64 + col]));
    red[tid] = m;
    __syncthreads();
    if (tid < 64) {
        m = fmaxf(fmaxf(red[tid], red[tid + 64]), fmaxf(red[tid + 128], red[tid + 192]));
        out[g * 64 + tid] = m;
    }
}

extern "C" void kernel_launch(void* const* d_in, const int* in_sizes, int n_in,
                              void* d_out, int out_size, void* d_ws, size_t ws_size,
                              hipStream_t stream) {
    const float* x = (const float*)d_in[0];
    const int* ei = (const int*)d_in[1];
    const float* ea = (const float*)d_in[2];
    const int* batch = (const int*)d_in[3];
    const float* wfc = (const float*)d_in[4];
    const float* bfc = (const float*)d_in[5];
    const float* w1_0 = (const float*)d_in[6];
    const float* b1_0 = (const float*)d_in[7];
    const float* w2_0 = (const float*)d_in[8];
    const float* w3_0 = (const float*)d_in[9];
    const float* b3_0 = (const float*)d_in[10];
    const float* w1_1 = (const float*)d_in[11];
    const float* b1_1 = (const float*)d_in[12];
    const float* w2_1 = (const float*)d_in[13];
    const float* w3_1 = (const float*)d_in[14];
    const float* b3_1 = (const float*)d_in[15];
    const float* w1_2 = (const float*)d_in[16];
    const float* b1_2 = (const float*)d_in[17];
    const float* w2_2 = (const float*)d_in[18];
    const float* w3_2 = (const float*)d_in[19];
    const float* b3_2 = (const float*)d_in[20];
    float* out = (float*)d_out;

    char* ws = (char*)d_ws;
    float* ew      = (float*)(ws);                 // E f32      3.2 MB
    float* c       = (float*)(ws + 3200000);       // N f32
    int*   cursor  = (int*)  (ws + 3600000);       // N int
    int*   rowptr  = (int*)  (ws + 3800000);       // N+1 int
    int2*  csr     = (int2*) (ws + 4000128);       // E int2     6.4 MB
    u16*   xb      = (u16*)  (ws + 10400128);      // N*64 bf16  6.4 MB
    u16*   sb      = (u16*)  (ws + 16800128);      // N*128 bf16 12.8 MB
    u16*   chb     = (u16*)  (ws + 29600128);      // N*128 bf16 12.8 MB (reused per layer)
    u16*   h1      = (u16*)  (ws + 42400128);      // N*64 bf16  6.4 MB
    u16*   h2      = (u16*)  (ws + 48800128);      // N*128 bf16 12.8 MB
    u16*   h3      = (u16*)  (ws + 61600128);      // N*64 bf16  6.4 MB
    u16*   bp0     = (u16*)  (ws + 68000128);      // 24 KB packed weights L0
    u16*   bp1     = (u16*)  (ws + 68024704);      // 48 KB L1
    u16*   bp2     = (u16*)  (ws + 68073856);      // 48 KB L2
    int* blk_sums  = (int*)  (ws + 68123008);
    int* blk_offs  = (int*)  (ws + 68123520);
    // aliases into regions dead until the gathers run:
    u16* dst16   = chb;                        // 1.6 MB at head of chb
    u32* deg4    = (u32*)(ws + 31600128);      // 4*N u32 = 800 KB, chb+2MB
    u32* partial = (u32*)sb;                   // 256*12500 u32 = 12.8 MB

    conv_x_kernel<<<3125, 256, 0, stream>>>(x, xb);
    ew_kernel<<<(N_EDGES + 255) / 256, 256, 0, stream>>>(ea, wfc, bfc, ei, ew, dst16);
    pack_w_kernel<<<30, 256, 0, stream>>>(w3_0, w1_0, w2_0, w3_1, w1_1, w2_1,
                                          w3_2, w1_2, w2_2, bp0, bp1, bp2);
    deg_hist_kernel<<<HCHUNKS * 2, 256, 0, stream>>>(dst16, partial);
    deg_reduce_kernel<<<dim3(98, 4), 256, 0, stream>>>(partial, deg4);
    scan1_kernel<<<SCAN_NB, 256, 0, stream>>>(deg4, rowptr, blk_sums);
    scan2_kernel<<<1, 128, 0, stream>>>(blk_sums, blk_offs, rowptr);
    scan3_kernel<<<(N_NODES + 255) / 256, 256, 0, stream>>>(rowptr, blk_offs, cursor);
    place_kernel<<<782 * NPASS, 256, 0, stream>>>(ei, ew, dst16, cursor, csr);

    const int RB = (N_NODES + 63) / 64;           // 782 row-blocks
    const int GBLK = (N_NODES * 64 + 255) / 256;  // one wave per node

    // layer 0: 64 -> 64
    gather_kernel<64, true><<<GBLK, 256, 0, stream>>>(xb, rowptr, csr, sb, chb, c);
    gemm_mfma<64, 64><<<dim3(RB, 1), 256, 0, stream>>>(xb, sb, chb, bp0, c, b1_0, b3_0, h1);

    // layer 1: 64 -> 128
    gather_kernel<64, false><<<GBLK, 256, 0, stream>>>(h1, rowptr, csr, sb, chb, c);
    gemm_mfma<64, 128><<<dim3(RB, 2), 256, 0, stream>>>(h1, sb, chb, bp1, c, b1_1, b3_1, h2);

    // layer 2: 128 -> 64
    gather_kernel<128, false><<<GBLK, 256, 0, stream>>>(h2, rowptr, csr, sb, chb, c);
    gemm_mfma<128, 64><<<dim3(RB, 1), 256, 0, stream>>>(h2, sb, chb, bp2, c, b1_2, b3_2, h3);

    // global max pool
    pool_kernel<<<NUM_GRAPHS_, 256, 0, stream>>>(h3, batch, out);
}

// Round 10
// 349.695 us; speedup vs baseline: 1.4025x; 1.0576x over previous
//
#include <hip/hip_runtime.h>
#include <math.h>

#define N_NODES 50000
#define N_EDGES 800000
#define NUM_GRAPHS_ 128
#define SCAN_NB 98   // ceil(50000/512)
#define NPASS 8
#define NODES_PER_PASS 6250  // 50000/8
#define HCHUNKS 128
#define EDGES_PER_CHUNK 6250 // 800000/128
#define HWORDS 12500         // 25000 nodes per half, 2 per word

typedef unsigned short u16;
typedef unsigned int u32;
typedef __attribute__((ext_vector_type(8))) short bf16x8;   // 8 bf16 (4 VGPRs)
typedef __attribute__((ext_vector_type(4))) float f32x4;    // 4 fp32

__device__ __forceinline__ float elu_f(float v) {
    return v > 0.f ? v : (__expf(v) - 1.f);
}
__device__ __forceinline__ u16 f2bf(float f) {  // RNE
    u32 u = __float_as_uint(f);
    u += 0x7FFFu + ((u >> 16) & 1u);
    return (u16)(u >> 16);
}
__device__ __forceinline__ float bf2f(u16 h) {
    return __uint_as_float(((u32)h) << 16);
}
__device__ __forceinline__ void bfpair(u32 v, float& lo, float& hi) {
    lo = __uint_as_float(v << 16);
    hi = __uint_as_float(v & 0xFFFF0000u);
}
__device__ __forceinline__ u32 packbf(float lo, float hi) {
    return (u32)f2bf(lo) | ((u32)f2bf(hi) << 16);
}

// ---------------------------------------------------------------------------
// xb = bf16(x)
// ---------------------------------------------------------------------------
__global__ void conv_x_kernel(const float* __restrict__ x, u16* __restrict__ xb) {
    int g = blockIdx.x * blockDim.x + threadIdx.x;
    float4 v = ((const float4*)x)[g];
    uint2 o;
    o.x = packbf(v.x, v.y);
    o.y = packbf(v.z, v.w);
    ((uint2*)xb)[g] = o;
}

// ---------------------------------------------------------------------------
// ew[e] = edge_attr[e,:16] . w_fc1 + b_fc1 ; dst16[e] = dst.  NO atomics.
// ---------------------------------------------------------------------------
__global__ void ew_kernel(const float* __restrict__ edge_attr,
                          const float* __restrict__ w_fc1,
                          const float* __restrict__ b_fc1,
                          const int* __restrict__ edge_index,
                          float* __restrict__ ew,
                          u16* __restrict__ dst16) {
    int e = blockIdx.x * blockDim.x + threadIdx.x;
    if (e >= N_EDGES) return;
    const float4* ea = (const float4*)(edge_attr + (size_t)e * 16);
    const float4* wf = (const float4*)w_fc1;
    float acc = b_fc1[0];
#pragma unroll
    for (int i = 0; i < 4; i++) {
        float4 a = ea[i], w = wf[i];
        acc += a.x * w.x + a.y * w.y + a.z * w.z + a.w * w.w;
    }
    ew[e] = acc;
    dst16[e] = (u16)edge_index[N_EDGES + e];
}

// ---------------------------------------------------------------------------
// Degree histogram per (chunk, half): LDS atomics only, dense write.
// ---------------------------------------------------------------------------
__global__ __launch_bounds__(256) void deg_hist_kernel(const u16* __restrict__ dst16,
                                                       u32* __restrict__ partial) {
    __shared__ u32 bins[HWORDS];
    const int c = blockIdx.x >> 1;
    const int p = blockIdx.x & 1;
    const int t = threadIdx.x;
    for (int i = t; i < HWORDS; i += 256) bins[i] = 0;
    __syncthreads();
    const int base = c * EDGES_PER_CHUNK;
    const int nlo = p * 25000;
    for (int i = t; i < EDGES_PER_CHUNK; i += 256) {
        const int b = (int)dst16[base + i] - nlo;
        if ((unsigned)b < 25000u)
            atomicAdd(&bins[b >> 1], 1u << ((b & 1) * 16));
    }
    __syncthreads();
    u32* outp = partial + (size_t)blockIdx.x * HWORDS;
    for (int i = t; i < HWORDS; i += 256) outp[i] = bins[i];
}

// ---------------------------------------------------------------------------
// Exclusive scan along the chunk axis: prefpack[c][node-pair] = count of this
// node's edges in chunks < c (packed u16 pair). degpack = total (= degree).
// ---------------------------------------------------------------------------
__global__ __launch_bounds__(256) void scan_chunks_kernel(const u32* __restrict__ partial,
                                                          u32* __restrict__ prefpack,
                                                          u32* __restrict__ degpack) {
    const int g = blockIdx.x * 256 + threadIdx.x;  // node-pair index 0..24999
    if (g >= 25000) return;
    const int p = (g >= HWORDS) ? 1 : 0;
    const int wh = g - p * HWORDS;
    u32 runlo = 0, runhi = 0;
    for (int c = 0; c < HCHUNKS; c++) {
        prefpack[(size_t)c * 25000 + g] = runlo | (runhi << 16);
        u32 v = partial[(size_t)((c << 1) + p) * HWORDS + wh];
        runlo += v & 0xFFFFu;
        runhi += v >> 16;
    }
    degpack[g] = runlo | (runhi << 16);
}

// ---------------------------------------------------------------------------
// Hierarchical exclusive scan of degpack -> rowptr[N+1]
// ---------------------------------------------------------------------------
__global__ __launch_bounds__(256) void scan1_kernel(const u32* __restrict__ degpack,
                                                    int* __restrict__ rowptr,
                                                    int* __restrict__ blk_sums) {
    __shared__ int sh[256];
    const int t = threadIdx.x;
    const int base = blockIdx.x * 512;
    const int i0 = base + 2 * t, i1 = i0 + 1;
    int d0 = 0, d1 = 0;
    if (i0 < N_NODES) {
        u32 v = degpack[i0 >> 1];
        d0 = (int)(v & 0xFFFFu);
        d1 = (int)(v >> 16);
    }
    const int pair = d0 + d1;
    int v = pair;
    sh[t] = v;
    __syncthreads();
#pragma unroll
    for (int off = 1; off < 256; off <<= 1) {
        int add = (t >= off) ? sh[t - off] : 0;
        __syncthreads();
        v += add;
        sh[t] = v;
        __syncthreads();
    }
    const int excl = v - pair;
    if (i0 < N_NODES) rowptr[i0] = excl;
    if (i1 < N_NODES) rowptr[i1] = excl + d0;
    if (t == 255) blk_sums[blockIdx.x] = v;
}

__global__ __launch_bounds__(128) void scan2_kernel(const int* __restrict__ blk_sums,
                                                    int* __restrict__ blk_offs,
                                                    int* __restrict__ rowptr) {
    __shared__ int sh[128];
    const int t = threadIdx.x;
    const int orig = (t < SCAN_NB) ? blk_sums[t] : 0;
    int v = orig;
    sh[t] = v;
    __syncthreads();
#pragma unroll
    for (int off = 1; off < 128; off <<= 1) {
        int add = (t >= off) ? sh[t - off] : 0;
        __syncthreads();
        v += add;
        sh[t] = v;
        __syncthreads();
    }
    if (t < SCAN_NB) blk_offs[t] = v - orig;
    if (t == 127) rowptr[N_NODES] = v;
}

__global__ void scan3_kernel(int* __restrict__ rowptr,
                             const int* __restrict__ blk_offs) {
    int i = blockIdx.x * blockDim.x + threadIdx.x;
    if (i >= N_NODES) return;
    rowptr[i] += blk_offs[i >> 9];
}

// ---------------------------------------------------------------------------
// CSR placement, NO global atomics (counting sort).
// Block (chunk c, pass p): slot = rowptr[d] + prefpack[c][d] + LDS local rank.
// pass = blockIdx&7 keeps each pass's 800KB csr region on one XCD.
// ---------------------------------------------------------------------------
__global__ __launch_bounds__(256) void place_kernel(const int* __restrict__ edge_index,
                                                    const float* __restrict__ ew,
                                                    const u16* __restrict__ dst16,
                                                    const int* __restrict__ rowptr,
                                                    const u32* __restrict__ prefpack,
                                                    int2* __restrict__ csr) {
    __shared__ int lcur[NODES_PER_PASS];
    const int pass = blockIdx.x & (NPASS - 1);
    const int c = blockIdx.x >> 3;
    const int lo = pass * NODES_PER_PASS;
    const int t = threadIdx.x;
    for (int i = t; i < NODES_PER_PASS; i += 256) lcur[i] = 0;
    __syncthreads();
    const int base = c * EDGES_PER_CHUNK;
    for (int i = t; i < EDGES_PER_CHUNK; i += 256) {
        const int e = base + i;
        const int d = (int)dst16[e];
        const int dl = d - lo;
        if ((unsigned)dl < (unsigned)NODES_PER_PASS) {
            u32 pw = prefpack[(size_t)c * 25000 + (d >> 1)];
            int pref = (int)((pw >> ((d & 1) * 16)) & 0xFFFFu);
            int lpos = atomicAdd(&lcur[dl], 1);
            int2 ent;
            ent.x = edge_index[e];
            ent.y = __float_as_int(ew[e]);
            csr[rowptr[d] + pref + lpos] = ent;
        }
    }
}

// ---------------------------------------------------------------------------
// Gather aggregation (bf16, fp32 accumulate), one WAVE per node. Layers 0/1.
// Writes s and ch = c*h; layer 0 also emits c.
// ---------------------------------------------------------------------------
template <int DIN, bool WRITE_C>
__global__ __launch_bounds__(256) void gather_kernel(
    const u16* __restrict__ xb, const int* __restrict__ rowptr,
    const int2* __restrict__ csr, u16* __restrict__ sb,
    u16* __restrict__ chb, float* __restrict__ c) {
    constexpr int CG = DIN / 4;
    constexpr int EG = 64 / CG;
    const int gid = blockIdx.x * 256 + threadIdx.x;
    const int node = gid >> 6;
    if (node >= N_NODES) return;
    const int lane = threadIdx.x & 63;
    const int cg = lane & (CG - 1);
    const int eg = lane / CG;
    const int beg = rowptr[node];
    const int end = rowptr[node + 1];
    const uint2* x2 = (const uint2*)xb;

    float a0 = 0.f, a1 = 0.f, a2 = 0.f, a3 = 0.f;
    float b0 = 0.f, b1 = 0.f, b2 = 0.f, b3 = 0.f;
    float wsum = 0.f;

    int p = beg + eg;
    for (; p + EG < end; p += 2 * EG) {
        int2 e0 = csr[p];
        int2 e1 = csr[p + EG];
        float w0 = __int_as_float(e0.y);
        float w1 = __int_as_float(e1.y);
        uint2 v0 = x2[(size_t)e0.x * CG + cg];
        uint2 v1 = x2[(size_t)e1.x * CG + cg];
        float f0, f1, f2, f3, g0, g1, g2, g3;
        bfpair(v0.x, f0, f1); bfpair(v0.y, f2, f3);
        bfpair(v1.x, g0, g1); bfpair(v1.y, g2, g3);
        a0 += w0 * f0; a1 += w0 * f1; a2 += w0 * f2; a3 += w0 * f3;
        b0 += w1 * g0; b1 += w1 * g1; b2 += w1 * g2; b3 += w1 * g3;
        wsum += w0 + w1;
    }
    if (p < end) {
        int2 e0 = csr[p];
        float w0 = __int_as_float(e0.y);
        uint2 v0 = x2[(size_t)e0.x * CG + cg];
        float f0, f1, f2, f3;
        bfpair(v0.x, f0, f1); bfpair(v0.y, f2, f3);
        a0 += w0 * f0; a1 += w0 * f1; a2 += w0 * f2; a3 += w0 * f3;
        wsum += w0;
    }
    a0 += b0; a1 += b1; a2 += b2; a3 += b3;

#pragma unroll
    for (int off = 32; off >= CG; off >>= 1) {
        a0 += __shfl_xor(a0, off);
        a1 += __shfl_xor(a1, off);
        a2 += __shfl_xor(a2, off);
        a3 += __shfl_xor(a3, off);
        wsum += __shfl_xor(wsum, off);
    }

    if (lane < CG) {
        uint2 so;
        so.x = packbf(a0, a1);
        so.y = packbf(a2, a3);
        ((uint2*)sb)[(size_t)node * CG + cg] = so;
        const float cn = WRITE_C ? wsum : c[node];
        uint2 hv = x2[(size_t)node * CG + cg];
        float h0, h1, h2, h3;
        bfpair(hv.x, h0, h1); bfpair(hv.y, h2, h3);
        uint2 co;
        co.x = packbf(cn * h0, cn * h1);
        co.y = packbf(cn * h2, cn * h3);
        ((uint2*)chb)[(size_t)node * CG + cg] = co;
    }
    if (WRITE_C && lane == 0) c[node] = wsum;
}

// ---------------------------------------------------------------------------
// Pack weights into MFMA B-frag layout (bf16).
// L0: [w3;w1;-w2] K=192 DOUT=64 ; L1: same K=192 DOUT=128
// L2: WIDE [w3 | -w2 | w1] K=128 DOUT=192
// ---------------------------------------------------------------------------
__global__ void pack_w_kernel(const float* __restrict__ w3_0, const float* __restrict__ w1_0, const float* __restrict__ w2_0,
                              const float* __restrict__ w3_1, const float* __restrict__ w1_1, const float* __restrict__ w2_1,
                              const float* __restrict__ w3_2, const float* __restrict__ w1_2, const float* __restrict__ w2_2,
                              u16* __restrict__ bp0, u16* __restrict__ bp1, u16* __restrict__ bp2) {
    int t = blockIdx.x * blockDim.x + threadIdx.x;
    if (t >= 7680) return;
    u16 buf[8];
    if (t < 4608) {
        // layers 0/1: K-concatenated [w3;w1;-w2]
        int DIN, DOUT, lid;
        const float *w3, *w1, *w2;
        u16* bp;
        if (t < 1536) { DIN = 64; DOUT = 64;  lid = t;        w3 = w3_0; w1 = w1_0; w2 = w2_0; bp = bp0; }
        else          { DIN = 64; DOUT = 128; lid = t - 1536; w3 = w3_1; w1 = w1_1; w2 = w2_1; bp = bp1; }
        const int NT = DOUT / 16;
        const int lane = lid & 63;
        const int fragid = lid >> 6;
        const int chunk = fragid / NT;
        const int ntile = fragid % NT;
        const int n = ntile * 16 + (lane & 15);
        const int kbase = chunk * 32 + (lane >> 4) * 8;
#pragma unroll
        for (int j = 0; j < 8; j++) {
            int k = kbase + j;
            int region = k / DIN;
            int kk = k - region * DIN;
            float v = (region == 0) ? w3[kk * DOUT + n]
                    : (region == 1) ? w1[kk * DOUT + n]
                                    : -w2[kk * DOUT + n];
            buf[j] = f2bf(v);
        }
        *(bf16x8*)(bp + ((size_t)lid << 3)) = *(bf16x8*)buf;
    } else {
        // layer 2 wide: N-concatenated [w3 | -w2 | w1], K=128, DOUT=192
        const int lid = t - 4608;          // 0..3071
        const int NT = 12;
        const int lane = lid & 63;
        const int fragid = lid >> 6;       // 0..47
        const int chunk = fragid / NT;     // 0..3
        const int ntile = fragid % NT;     // 0..11
        const int n = ntile * 16 + (lane & 15);   // 0..191
        const int kbase = chunk * 32 + (lane >> 4) * 8;  // 0..127
#pragma unroll
        for (int j = 0; j < 8; j++) {
            int k = kbase + j;
            float v = (n < 64)  ? w3_2[k * 64 + n]
                    : (n < 128) ? -w2_2[k * 64 + (n - 64)]
                                : w1_2[k * 64 + (n - 128)];
            buf[j] = f2bf(v);
        }
        *(bf16x8*)(bp2 + ((size_t)lid << 3)) = *(bf16x8*)buf;
    }
}

// ---------------------------------------------------------------------------
// MFMA GEMM (layers 0/1): out = elu( [h|s|ch] @ Bp + b3 + c*b1 )
// ---------------------------------------------------------------------------
template <int DIN, int DOUT>
__global__ __launch_bounds__(256) void gemm_mfma(
    const u16* __restrict__ hb, const u16* __restrict__ sb,
    const u16* __restrict__ chb, const u16* __restrict__ Bp,
    const float* __restrict__ cvec, const float* __restrict__ bias1,
    const float* __restrict__ bias3, u16* __restrict__ outp) {
    constexpr int CH = DIN / 32;
    constexpr int CHUNKS = 3 * CH;
    constexpr int NT = DOUT / 16;
    const int tid = threadIdx.x;
    const int wv = tid >> 6;
    const int lane = tid & 63;
    const int l15 = lane & 15;
    const int q = lane >> 4;
    const int mhalf = wv & 1;
    const int nhalf = wv >> 1;
    const int row_base = blockIdx.x * 64 + mhalf * 32;
    const int nt0 = blockIdx.y * 4 + nhalf * 2;

    const int r0 = min(row_base + l15, N_NODES - 1);
    const int r1 = min(row_base + 16 + l15, N_NODES - 1);
    const int qo = q * 8;

    f32x4 acc00 = {0.f, 0.f, 0.f, 0.f};
    f32x4 acc01 = {0.f, 0.f, 0.f, 0.f};
    f32x4 acc10 = {0.f, 0.f, 0.f, 0.f};
    f32x4 acc11 = {0.f, 0.f, 0.f, 0.f};

#pragma unroll
    for (int chunk = 0; chunk < CHUNKS; chunk++) {
        const int region = chunk / CH;
        const int koff = (chunk - region * CH) * 32 + qo;
        const u16* A = (region == 0) ? hb : (region == 1) ? sb : chb;
        bf16x8 a0 = *(const bf16x8*)(A + (size_t)r0 * DIN + koff);
        bf16x8 a1 = *(const bf16x8*)(A + (size_t)r1 * DIN + koff);
        const u16* bp = Bp + (((size_t)(chunk * NT + nt0) * 64 + lane) << 3);
        bf16x8 bf0 = *(const bf16x8*)bp;
        bf16x8 bf1 = *(const bf16x8*)(bp + 64 * 8);
        acc00 = __builtin_amdgcn_mfma_f32_16x16x32_bf16(a0, bf0, acc00, 0, 0, 0);
        acc01 = __builtin_amdgcn_mfma_f32_16x16x32_bf16(a0, bf1, acc01, 0, 0, 0);
        acc10 = __builtin_amdgcn_mfma_f32_16x16x32_bf16(a1, bf0, acc10, 0, 0, 0);
        acc11 = __builtin_amdgcn_mfma_f32_16x16x32_bf16(a1, bf1, acc11, 0, 0, 0);
    }

#pragma unroll
    for (int ni = 0; ni < 2; ni++) {
        const int col = (nt0 + ni) * 16 + l15;
        const float B3 = bias3[col];
        const float B1 = bias1[col];
        const f32x4 am0 = ni ? acc01 : acc00;
        const f32x4 am1 = ni ? acc11 : acc10;
#pragma unroll
        for (int mi = 0; mi < 2; mi++) {
            const f32x4 av = mi ? am1 : am0;
#pragma unroll
            for (int reg = 0; reg < 4; reg++) {
                const int row = row_base + mi * 16 + q * 4 + reg;
                if (row < N_NODES) {
                    const float cv = cvec[row];
                    const float val = av[reg] + B3 + cv * B1;
                    outp[(size_t)row * DOUT + col] = f2bf(elu_f(val));
                }
            }
        }
    }
}

// ---------------------------------------------------------------------------
// Layer-2 wide GEMM: zuy = h2 @ [w3 | -w2 | w1]  (K=128, DOUT=192, no epi)
// ---------------------------------------------------------------------------
__global__ __launch_bounds__(256) void gemm_wide_kernel(
    const u16* __restrict__ hb, const u16* __restrict__ Bp,
    u16* __restrict__ zuy) {
    constexpr int NT = 12;
    const int tid = threadIdx.x;
    const int wv = tid >> 6;
    const int lane = tid & 63;
    const int l15 = lane & 15;
    const int q = lane >> 4;
    const int row_base = blockIdx.x * 64 + (wv & 1) * 32;
    const int nt0 = blockIdx.y * 4 + (wv >> 1) * 2;

    const int r0 = min(row_base + l15, N_NODES - 1);
    const int r1 = min(row_base + 16 + l15, N_NODES - 1);
    const int qo = q * 8;

    f32x4 acc00 = {0.f, 0.f, 0.f, 0.f};
    f32x4 acc01 = {0.f, 0.f, 0.f, 0.f};
    f32x4 acc10 = {0.f, 0.f, 0.f, 0.f};
    f32x4 acc11 = {0.f, 0.f, 0.f, 0.f};

#pragma unroll
    for (int chunk = 0; chunk < 4; chunk++) {
        const int koff = chunk * 32 + qo;
        bf16x8 a0 = *(const bf16x8*)(hb + (size_t)r0 * 128 + koff);
        bf16x8 a1 = *(const bf16x8*)(hb + (size_t)r1 * 128 + koff);
        const u16* bp = Bp + (((size_t)(chunk * NT + nt0) * 64 + lane) << 3);
        bf16x8 bf0 = *(const bf16x8*)bp;
        bf16x8 bf1 = *(const bf16x8*)(bp + 64 * 8);
        acc00 = __builtin_amdgcn_mfma_f32_16x16x32_bf16(a0, bf0, acc00, 0, 0, 0);
        acc01 = __builtin_amdgcn_mfma_f32_16x16x32_bf16(a0, bf1, acc01, 0, 0, 0);
        acc10 = __builtin_amdgcn_mfma_f32_16x16x32_bf16(a1, bf0, acc10, 0, 0, 0);
        acc11 = __builtin_amdgcn_mfma_f32_16x16x32_bf16(a1, bf1, acc11, 0, 0, 0);
    }

#pragma unroll
    for (int ni = 0; ni < 2; ni++) {
        const int col = (nt0 + ni) * 16 + l15;
        const f32x4 am0 = ni ? acc01 : acc00;
        const f32x4 am1 = ni ? acc11 : acc10;
#pragma unroll
        for (int mi = 0; mi < 2; mi++) {
            const f32x4 av = mi ? am1 : am0;
#pragma unroll
            for (int reg = 0; reg < 4; reg++) {
                const int row = row_base + mi * 16 + q * 4 + reg;
                if (row < N_NODES)
                    zuy[(size_t)row * 192 + col] = f2bf(av[reg]);
            }
        }
    }
}

// ---------------------------------------------------------------------------
// Layer-2 gather + fused epilogue. zuy rows: [z(64) | u(64) | y(64)].
// h3[i] = elu( z_i + c_i*u_i + sum_e w_e * y[src_e] + b3 + c_i*b1 )
// ---------------------------------------------------------------------------
__global__ __launch_bounds__(256) void gather2_kernel(
    const u16* __restrict__ zuy, const int* __restrict__ rowptr,
    const int2* __restrict__ csr, const float* __restrict__ c,
    const float* __restrict__ bias1, const float* __restrict__ bias3,
    u16* __restrict__ h3) {
    constexpr int CG = 16, EG = 4;
    const int gid = blockIdx.x * 256 + threadIdx.x;
    const int node = gid >> 6;
    if (node >= N_NODES) return;
    const int lane = threadIdx.x & 63;
    const int cg = lane & (CG - 1);
    const int eg = lane >> 4;
    const int beg = rowptr[node];
    const int end = rowptr[node + 1];

    float a0 = 0.f, a1 = 0.f, a2 = 0.f, a3 = 0.f;
    float b0 = 0.f, b1 = 0.f, b2 = 0.f, b3 = 0.f;

    int p = beg + eg;
    for (; p + EG < end; p += 2 * EG) {
        int2 e0 = csr[p];
        int2 e1 = csr[p + EG];
        float w0 = __int_as_float(e0.y);
        float w1 = __int_as_float(e1.y);
        uint2 v0 = ((const uint2*)(zuy + (size_t)e0.x * 192 + 128))[cg];
        uint2 v1 = ((const uint2*)(zuy + (size_t)e1.x * 192 + 128))[cg];
        float f0, f1, f2, f3, g0, g1, g2, g3;
        bfpair(v0.x, f0, f1); bfpair(v0.y, f2, f3);
        bfpair(v1.x, g0, g1); bfpair(v1.y, g2, g3);
        a0 += w0 * f0; a1 += w0 * f1; a2 += w0 * f2; a3 += w0 * f3;
        b0 += w1 * g0; b1 += w1 * g1; b2 += w1 * g2; b3 += w1 * g3;
    }
    if (p < end) {
        int2 e0 = csr[p];
        float w0 = __int_as_float(e0.y);
        uint2 v0 = ((const uint2*)(zuy + (size_t)e0.x * 192 + 128))[cg];
        float f0, f1, f2, f3;
        bfpair(v0.x, f0, f1); bfpair(v0.y, f2, f3);
        a0 += w0 * f0; a1 += w0 * f1; a2 += w0 * f2; a3 += w0 * f3;
    }
    a0 += b0; a1 += b1; a2 += b2; a3 += b3;

#pragma unroll
    for (int off = 32; off >= CG; off >>= 1) {
        a0 += __shfl_xor(a0, off);
        a1 += __shfl_xor(a1, off);
        a2 += __shfl_xor(a2, off);
        a3 += __shfl_xor(a3, off);
    }

    if (lane < CG) {
        const float cn = c[node];
        const u16* zr = zuy + (size_t)node * 192;
        uint2 zv = ((const uint2*)zr)[cg];
        uint2 uv = ((const uint2*)(zr + 64))[cg];
        float z0, z1, z2, z3, u0, u1, u2, u3;
        bfpair(zv.x, z0, z1); bfpair(zv.y, z2, z3);
        bfpair(uv.x, u0, u1); bfpair(uv.y, u2, u3);
        const float4 b3v = *(const float4*)(bias3 + cg * 4);
        const float4 b1v = *(const float4*)(bias1 + cg * 4);
        float o0 = elu_f(z0 + cn * u0 + a0 + b3v.x + cn * b1v.x);
        float o1 = elu_f(z1 + cn * u1 + a1 + b3v.y + cn * b1v.y);
        float o2 = elu_f(z2 + cn * u2 + a2 + b3v.z + cn * b1v.z);
        float o3 = elu_f(z3 + cn * u3 + a3 + b3v.w + cn * b1v.w);
        uint2 o;
        o.x = packbf(o0, o1);
        o.y = packbf(o2, o3);
        ((uint2*)h3)[(size_t)node * CG + cg] = o;
    }
}

// ---------------------------------------------------------------------------
// out[g, :] = max over nodes of graph g of h[:, :64] (bf16 in, fp32 out)
// ---------------------------------------------------------------------------
__global__ void pool_kernel(const u16* __restrict__ h,
                            const int* __restrict__ batch,
                            float* __restrict__ out) {
    const int g = blockIdx.x;
    const int tid = threadIdx.x;
    int lo = 0, hi = N_NODES;
    while (lo < hi) { int mid = (lo + hi) >> 1; if (batch[mid] < g) lo = mid + 1; else hi = mid; }
    const int beg = lo;
    lo = beg; hi = N_NODES;
    while (lo < hi) { int mid = (lo + hi) >> 1; if (batch[mid] < g + 1) lo = mid + 1; else hi = mid; }
    const int end = lo;

    __shared__ float red[256];
    const int col = tid & 63;
    const int rg = tid >> 6;
    float m = -3.0e38f;
    for (int r = beg + rg; r < end; r += 4) m = fmaxf(m, bf2f(h[(size_t)r * 64 + col]));
    red[tid] = m;
    __syncthreads();
    if (tid < 64) {
        m = fmaxf(fmaxf(red[tid], red[tid + 64]), fmaxf(red[tid + 128], red[tid + 192]));
        out[g * 64 + tid] = m;
    }
}

extern "C" void kernel_launch(void* const* d_in, const int* in_sizes, int n_in,
                              void* d_out, int out_size, void* d_ws, size_t ws_size,
                              hipStream_t stream) {
    const float* x = (const float*)d_in[0];
    const int* ei = (const int*)d_in[1];
    const float* ea = (const float*)d_in[2];
    const int* batch = (const int*)d_in[3];
    const float* wfc = (const float*)d_in[4];
    const float* bfc = (const float*)d_in[5];
    const float* w1_0 = (const float*)d_in[6];
    const float* b1_0 = (const float*)d_in[7];
    const float* w2_0 = (const float*)d_in[8];
    const float* w3_0 = (const float*)d_in[9];
    const float* b3_0 = (const float*)d_in[10];
    const float* w1_1 = (const float*)d_in[11];
    const float* b1_1 = (const float*)d_in[12];
    const float* w2_1 = (const float*)d_in[13];
    const float* w3_1 = (const float*)d_in[14];
    const float* b3_1 = (const float*)d_in[15];
    const float* w1_2 = (const float*)d_in[16];
    const float* b1_2 = (const float*)d_in[17];
    const float* w2_2 = (const float*)d_in[18];
    const float* w3_2 = (const float*)d_in[19];
    const float* b3_2 = (const float*)d_in[20];
    float* out = (float*)d_out;

    char* ws = (char*)d_ws;
    float* ew      = (float*)(ws);                 // E f32      3.2 MB
    float* c       = (float*)(ws + 3200000);       // N f32
    int*   rowptr  = (int*)  (ws + 3800000);       // N+1 int
    int2*  csr     = (int2*) (ws + 4000128);       // E int2     6.4 MB
    u16*   xb      = (u16*)  (ws + 10400128);      // N*64 bf16  6.4 MB
    u16*   sb      = (u16*)  (ws + 16800128);      // N*128 bf16 12.8 MB
    u16*   chb     = (u16*)  (ws + 29600128);      // N*128 bf16 12.8 MB
    u16*   h1      = (u16*)  (ws + 42400128);      // N*64 bf16  6.4 MB
    u16*   h2      = (u16*)  (ws + 48800128);      // N*128 bf16 12.8 MB
    u16*   h3      = (u16*)  (ws + 61600128);      // N*64 bf16  6.4 MB
    u16*   bp0     = (u16*)  (ws + 68000128);      // 24 KB packed weights L0
    u16*   bp1     = (u16*)  (ws + 68024704);      // 48 KB L1
    u16*   bp2     = (u16*)  (ws + 68073856);      // 48 KB L2 wide
    int* blk_sums  = (int*)  (ws + 68123008);
    int* blk_offs  = (int*)  (ws + 68123520);
    // aliases into regions dead at time of use:
    u16* dst16   = chb;                        // 1.6 MB, dead before gather0
    u32* degpack = (u32*)(ws + 31600128);      // 100 KB (chb+2MB), dead before gather0
    u32* partial = (u32*)sb;                   // 12.8 MB, dead before gather0
    u32* prefpack = (u32*)h2;                  // 12.8 MB, dead before gemm L1 writes h2
    u16* zuy     = sb;                         // N*192 bf16 = 19.2 MB over sb+chb (dead after gemm L1)

    conv_x_kernel<<<3125, 256, 0, stream>>>(x, xb);
    ew_kernel<<<(N_EDGES + 255) / 256, 256, 0, stream>>>(ea, wfc, bfc, ei, ew, dst16);
    pack_w_kernel<<<30, 256, 0, stream>>>(w3_0, w1_0, w2_0, w3_1, w1_1, w2_1,
                                          w3_2, w1_2, w2_2, bp0, bp1, bp2);
    deg_hist_kernel<<<HCHUNKS * 2, 256, 0, stream>>>(dst16, partial);
    scan_chunks_kernel<<<98, 256, 0, stream>>>(partial, prefpack, degpack);
    scan1_kernel<<<SCAN_NB, 256, 0, stream>>>(degpack, rowptr, blk_sums);
    scan2_kernel<<<1, 128, 0, stream>>>(blk_sums, blk_offs, rowptr);
    scan3_kernel<<<(N_NODES + 255) / 256, 256, 0, stream>>>(rowptr, blk_offs);
    place_kernel<<<HCHUNKS * NPASS, 256, 0, stream>>>(ei, ew, dst16, rowptr, prefpack, csr);

    const int RB = (N_NODES + 63) / 64;           // 782 row-blocks
    const int GBLK = (N_NODES * 64 + 255) / 256;  // one wave per node

    // layer 0: 64 -> 64
    gather_kernel<64, true><<<GBLK, 256, 0, stream>>>(xb, rowptr, csr, sb, chb, c);
    gemm_mfma<64, 64><<<dim3(RB, 1), 256, 0, stream>>>(xb, sb, chb, bp0, c, b1_0, b3_0, h1);

    // layer 1: 64 -> 128
    gather_kernel<64, false><<<GBLK, 256, 0, stream>>>(h1, rowptr, csr, sb, chb, c);
    gemm_mfma<64, 128><<<dim3(RB, 2), 256, 0, stream>>>(h1, sb, chb, bp1, c, b1_1, b3_1, h2);

    // layer 2: 128 -> 64, restructured: wide gemm then output-space gather
    gemm_wide_kernel<<<dim3(RB, 3), 256, 0, stream>>>(h2, bp2, zuy);
    gather2_kernel<<<GBLK, 256, 0, stream>>>(zuy, rowptr, csr, c, b1_2, b3_2, h3);

    // global max pool
    pool_kernel<<<NUM_GRAPHS_, 256, 0, stream>>>(h3, batch, out);
}